// Round 4
// baseline (1139.470 us; speedup 1.0000x reference)
//
#include <hip/hip_runtime.h>
#include <hip/hip_bf16.h>

#define Bb 8
#define Tt 600
#define Cc 8
#define Ff 257
#define TAPS 5
#define DELAY 3
#define KC 40            // TAPS*C
#define NC 48            // KC + C (R columns | P columns)
#define RPW 53           // RP row stride (float2): 106 dwords, gcd(106,32)=2 -> 16-bank row spread
#define TQ 593           // T - DELAY - TAPS + 1
#define TP 602           // Y LDS row stride (float2): conflict-free for channel-strided access
#define EPSF 1e-10f
#define NTOT (Bb*Tt*Cc*Ff)   // 9,868,800

__device__ __forceinline__ float2 cmul2(float2 a, float2 b) {
  return make_float2(a.x*b.x - a.y*b.y, a.x*b.y + a.y*b.x);
}

// acc += conj(a)*b with a pre-scaled: (ax,ay) = (w*y.x, w*y.y)
#define CMAC(acc, ax, ay, b)                    \
  acc.x = fmaf(ax, b.x, acc.x);                 \
  acc.x = fmaf(ay, b.y, acc.x);                 \
  acc.y = fmaf(ax, b.y, acc.y);                 \
  acc.y = fmaf(-(ay), b.x, acc.y);

// (B,T,C,F) re/im planes -> (B,F,C,T) interleaved float2
__global__ __launch_bounds__(256) void k_tin(const float* __restrict__ in_re,
                                             const float* __restrict__ in_im,
                                             float2* __restrict__ Yt) {
  __shared__ float2 tile[32][33];
  int f0 = blockIdx.x * 32, t0 = blockIdx.y * 32;
  int b = blockIdx.z >> 3, c = blockIdx.z & 7;
  int tx = threadIdx.x & 31, ty = threadIdx.x >> 5;
#pragma unroll
  for (int ii = 0; ii < 4; ++ii) {
    int t = t0 + ty + 8 * ii, f = f0 + tx;
    if (t < Tt && f < Ff) {
      size_t idx = (((size_t)b * Tt + t) * Cc + c) * Ff + f;
      tile[ty + 8 * ii][tx] = make_float2(in_re[idx], in_im[idx]);
    }
  }
  __syncthreads();
#pragma unroll
  for (int ii = 0; ii < 4; ++ii) {
    int f = f0 + ty + 8 * ii, t = t0 + tx;
    if (f < Ff && t < Tt) {
      size_t o = (((size_t)b * Ff + f) * Cc + c) * Tt + t;
      Yt[o] = tile[tx][ty + 8 * ii];
    }
  }
}

// Unrolled accumulation body; u is a literal 0..4 so all %5 indices fold.
#define ABODY(u) do {                                                     \
  float2 ynd = Yd[tb + (u) + 4];                                          \
  float2 yne = Ye[tb + (u) + 4];                                          \
  float2 yep = Ye[tb + (u) + 7];                                          \
  float w = wl[tb + (u) + 7];                                             \
  wd[((u)+4)%5] = ynd; we[((u)+4)%5] = yne;                               \
  float ax[5], ay[5];                                                     \
  _Pragma("unroll")                                                       \
  for (int k = 0; k < 5; ++k) {                                           \
    float2 yr = wd[((u)+4-k)%5]; ax[k] = w*yr.x; ay[k] = w*yr.y;          \
  }                                                                       \
  _Pragma("unroll")                                                       \
  for (int l = 0; l < 5; ++l) {                                           \
    float2 yc = we[((u)+4-l)%5];                                          \
    _Pragma("unroll")                                                     \
    for (int k = 0; k < 5; ++k) { CMAC(rac[k][l], ax[k], ay[k], yc); }    \
  }                                                                       \
  _Pragma("unroll")                                                       \
  for (int k = 0; k < 5; ++k) { CMAC(pac[k], ax[k], ay[k], yep); }        \
} while (0)

// One block (512 thr) per (b,f): full 2-iteration WPE.
// Accumulation: 64-thread groups, thread=(d,e) owns 5x5 R-tile + 5 P via
// register sliding windows; 8-way t-split; sequential wave merge; 1-barrier
// GJ solve.  XCD-chunked blockIdx swizzle: grid 2056 = 8*257; XCD x gets one
// full batch b=x, so adjacent-f blocks (which share output cache lines in
// direct mode) live on the SAME XCD L2 -> write-combining kills the 8-16x
// partial-line amplification of scattered (B,T,C,F) plane stores/loads.
// enh aliases Yt: each block stages its own Yt slice to LDS before writing it.
__global__ void __launch_bounds__(512, 4)
k_wpe(const float2* __restrict__ Yt,
      float2* __restrict__ enh,
      const float* __restrict__ in_re,
      const float* __restrict__ in_im,
      const int* __restrict__ ilens,
      float* __restrict__ out_re,
      float* __restrict__ out_im,
      int load_direct, int store_direct) {
  __shared__ float2 Yl[Cc][TP];        // 8 x 602 complex = 38528 B
  __shared__ float2 RP[KC][RPW];       // [R | P] 40 x 53      = 16960 B
  __shared__ float wl[Tt];             // 2400 B   -> total 57888 B

  // XCD-chunked bijective swizzle (2056 % 8 == 0): bf = (orig%8)*257 + orig/8
  int orig = blockIdx.x;
  int bf = (orig & 7) * (Bb * Ff / 8) + (orig >> 3);
  int b = bf / Ff, f = bf % Ff;
  int tid = threadIdx.x;               // 0..511
  int group = tid >> 6;                // t-split group (wave)
  int lane = tid & 63;
  int d = lane & 7;                    // row channel
  int e = lane >> 3;                   // col channel

  // solve mapping: thread = (row, col-chunk), 480 active
  int srow = tid % KC;                 // const divisor -> magic mul, hoisted
  int scol = tid / KC;                 // 0..12

  // ---- stage Y into LDS
  if (!load_direct) {
    const float4* Yg = (const float4*)(Yt + (size_t)bf * (Cc * Tt));
    for (int i = tid; i < Cc * Tt / 2; i += 512) {
      float4 v = Yg[i];
      int c = i / (Tt / 2), t2 = (i % (Tt / 2)) * 2;
      *(float4*)&Yl[c][t2] = v;        // 16B aligned: 602*c + t2 even
    }
  } else {
    for (int i = tid; i < Cc * Tt; i += 512) {
      int c = i / Tt, t = i % Tt;
      size_t idx = (((size_t)b * Tt + t) * Cc + c) * Ff + f;
      Yl[c][t] = make_float2(in_re[idx], in_im[idx]);
    }
  }
  __syncthreads();

  const float2* Yd = &Yl[d][0];
  const float2* Ye = &Yl[e][0];

  int tA = (TQ * group) >> 3;
  int tB = (TQ * (group + 1)) >> 3;

  for (int iter = 0; iter < 3; ++iter) {
    // ---- weights (iter 0 from Y); iter 1: apply filter -> weights; iter 2: apply -> store
    if (iter == 0) {
      for (int t = tid; t < Tt; t += 512) {
        float s = 0.f;
#pragma unroll
        for (int c = 0; c < Cc; ++c) { float2 y = Yl[c][t]; s += y.x*y.x + y.y*y.y; }
        wl[t] = 1.0f / fmaxf(s * 0.125f, EPSF);
      }
    } else {
      int il = (iter == 2 && store_direct) ? ilens[b] : Tt;
      for (int t = tid; t < Tt; t += 512) {
        float2 acc[Cc];
#pragma unroll
        for (int ee = 0; ee < Cc; ++ee) acc[ee] = Yl[ee][t];
        for (int p = 0; p < TAPS; ++p) {
          int ts = t - DELAY - p;
          if (ts < 0) break;   // zero-padded region
#pragma unroll
          for (int dd = 0; dd < Cc; ++dd) {
            float2 u = Yl[dd][ts];
#pragma unroll
            for (int ee = 0; ee < Cc; ++ee) {
              float2 g = RP[p * Cc + dd][KC + ee];  // uniform addr across wave -> broadcast
              acc[ee].x -= g.x*u.x - g.y*u.y;
              acc[ee].y -= g.x*u.y + g.y*u.x;
            }
          }
        }
        if (iter == 1) {
          float s = 0.f;
#pragma unroll
          for (int ee = 0; ee < Cc; ++ee) s += acc[ee].x*acc[ee].x + acc[ee].y*acc[ee].y;
          wl[t] = 1.0f / fmaxf(s * 0.125f, EPSF);
        } else {
          if (!store_direct) {
            float2* Eg = enh + (size_t)bf * (Cc * Tt);
#pragma unroll
            for (int ee = 0; ee < Cc; ++ee) Eg[ee * Tt + t] = acc[ee];  // own Yt slice
          } else {
            bool live = (t < il);
#pragma unroll
            for (int ee = 0; ee < Cc; ++ee) {
              float2 v = live ? acc[ee] : make_float2(0.f, 0.f);
              size_t idx = (((size_t)b * Tt + t) * Cc + ee) * Ff + f;
              out_re[idx] = v.x;
              out_im[idx] = v.y;
            }
          }
        }
      }
    }
    if (iter == 2) break;
    __syncthreads();   // (A) wl ready; apply-phase G reads done

    // ---- accumulate: per-thread 5x5+5 tile, register sliding windows
    float2 rac[5][5], pac[5];
#pragma unroll
    for (int k = 0; k < 5; ++k) {
#pragma unroll
      for (int l = 0; l < 5; ++l) rac[k][l] = make_float2(0.f, 0.f);
      pac[k] = make_float2(0.f, 0.f);
    }

    float2 wd[5], we[5];
#pragma unroll
    for (int i = 0; i < 4; ++i) { wd[i] = Yd[tA + i]; we[i] = Ye[tA + i]; }

    int tb = tA;
    for (; tb + 5 <= tB; tb += 5) {
      ABODY(0); ABODY(1); ABODY(2); ABODY(3); ABODY(4);
    }
    for (int t = tb; t < tB; ++t) {    // tail (<=4 iters): read fresh
      float2 yep = Ye[t + 7];
      float w = wl[t + 7];
      float ax[5], ay[5];
#pragma unroll
      for (int k = 0; k < 5; ++k) {
        float2 yr = Yd[t + 4 - k]; ax[k] = w*yr.x; ay[k] = w*yr.y;
      }
#pragma unroll
      for (int l = 0; l < 5; ++l) {
        float2 yc = Ye[t + 4 - l];
#pragma unroll
        for (int k = 0; k < 5; ++k) { CMAC(rac[k][l], ax[k], ay[k], yc); }
      }
#pragma unroll
      for (int k = 0; k < 5; ++k) { CMAC(pac[k], ax[k], ay[k], yep); }
    }

    // ---- merge the 8 group partials into RP (wave-uniform branch per pass).
    // Pass 0 WRITES (no zero-init needed) and folds the EPS regularizer onto
    // the diagonal (k==l && d==e). Plain LDS read/add/write: no FP atomics.
    for (int gpass = 0; gpass < 8; ++gpass) {
      if (group == gpass) {
        if (gpass == 0) {
#pragma unroll
          for (int k = 0; k < 5; ++k) {
#pragma unroll
            for (int l = 0; l < 5; ++l) {
              float2 v = rac[k][l];
              if (k == l && d == e) v.x += EPSF;
              RP[k*8+d][l*8+e] = v;
            }
            RP[k*8+d][KC+e] = pac[k];
          }
        } else {
#pragma unroll
          for (int k = 0; k < 5; ++k) {
#pragma unroll
            for (int l = 0; l < 5; ++l) {
              float2 v = RP[k*8+d][l*8+e];
              v.x += rac[k][l].x; v.y += rac[k][l].y;
              RP[k*8+d][l*8+e] = v;
            }
            float2 v = RP[k*8+d][KC+e];
            v.x += pac[k].x; v.y += pac[k].y;
            RP[k*8+d][KC+e] = v;
          }
        }
      }
      __syncthreads();
    }

    // ---- unnormalized Gauss-Jordan on [R | P]: ONE barrier per step.
    // Step j: rows i!=j:  RP[i][k] -= (RP[i][j]/RP[j][j]) * RP[j][k], k>j.
    // Row j and column j are never written during step j -> no intra-step hazard.
    for (int j = 0; j < KC; ++j) {
      if (tid < 480 && srow != j) {
        float2 pv = RP[j][j];
        float idn = 1.0f / (pv.x*pv.x + pv.y*pv.y);
        float2 lij = RP[srow][j];
        float2 fij = make_float2((lij.x*pv.x + lij.y*pv.y) * idn,
                                 (lij.y*pv.x - lij.x*pv.y) * idn);
        for (int k = j + 1 + scol; k < NC; k += 12) {
          float2 c = RP[j][k];
          float sx = fij.x*c.x - fij.y*c.y;
          float sy = fij.x*c.y + fij.y*c.x;
          RP[srow][k].x -= sx;
          RP[srow][k].y -= sy;
        }
      }
      __syncthreads();
    }
    // R is now diagonal; X = R^-1 P obtained by scaling P-columns by 1/diag
    if (tid < KC * Cc) {               // 320 entries
      int i = tid >> 3, ee = tid & 7;
      float2 pv = RP[i][i];
      float idn = 1.0f / (pv.x*pv.x + pv.y*pv.y);
      float2 p2 = RP[i][KC + ee];
      RP[i][KC + ee] = make_float2((p2.x*pv.x + p2.y*pv.y) * idn,
                                   (p2.y*pv.x - p2.x*pv.y) * idn);
    }
    __syncthreads();
  }
}

// (B,F,C,T) float2 -> masked (B,T,C,F) re/im planes
__global__ __launch_bounds__(256) void k_tout(const float2* __restrict__ enh,
                                              const int* __restrict__ ilens,
                                              float* __restrict__ out_re,
                                              float* __restrict__ out_im) {
  __shared__ float2 tile[32][33];
  int t0 = blockIdx.x * 32, f0 = blockIdx.y * 32;
  int b = blockIdx.z >> 3, c = blockIdx.z & 7;
  int tx = threadIdx.x & 31, ty = threadIdx.x >> 5;
#pragma unroll
  for (int ii = 0; ii < 4; ++ii) {
    int f = f0 + ty + 8 * ii, t = t0 + tx;
    if (f < Ff && t < Tt)
      tile[ty + 8 * ii][tx] = enh[(((size_t)b * Ff + f) * Cc + c) * Tt + t];
  }
  __syncthreads();
  int il = ilens[b];
#pragma unroll
  for (int ii = 0; ii < 4; ++ii) {
    int t = t0 + ty + 8 * ii, f = f0 + tx;
    if (t < Tt && f < Ff) {
      float2 v = tile[tx][ty + 8 * ii];
      if (t >= il) v = make_float2(0.f, 0.f);
      size_t idx = (((size_t)b * Tt + t) * Cc + c) * Ff + f;
      out_re[idx] = v.x;
      out_im[idx] = v.y;
    }
  }
}

extern "C" void kernel_launch(void* const* d_in, const int* in_sizes, int n_in,
                              void* d_out, int out_size, void* d_ws, size_t ws_size,
                              hipStream_t stream) {
  const float* in_re = (const float*)d_in[0];
  const float* in_im = (const float*)d_in[1];
  const int* ilens = (const int*)d_in[2];
  float* out_re = (float*)d_out;
  float* out_im = out_re + NTOT;

  size_t ybytes = (size_t)Bb * Ff * Cc * Tt * sizeof(float2);  // 78,950,400 B
  int have_yt = ws_size >= ybytes;
  // enh ALIASES Yt: k_wpe block bf stages Yt[bf] into LDS before writing enh[bf],
  // and no block touches another block's slice -> race-free, halves ws need.
  float2* Yt  = (float2*)d_ws;
  float2* enh = (float2*)d_ws;

  if (have_yt) {
    dim3 g((Ff + 31) / 32, (Tt + 31) / 32, Bb * Cc);
    k_tin<<<g, dim3(256), 0, stream>>>(in_re, in_im, Yt);
  }
  {
    dim3 g(Bb * Ff);
    k_wpe<<<g, dim3(512), 0, stream>>>(Yt, enh, in_re, in_im, ilens,
                                       out_re, out_im,
                                       have_yt ? 0 : 1, have_yt ? 0 : 1);
  }
  if (have_yt) {
    dim3 g((Tt + 31) / 32, (Ff + 31) / 32, Bb * Cc);
    k_tout<<<g, dim3(256), 0, stream>>>(enh, ilens, out_re, out_im);
  }
}

// Round 5
// 1034.346 us; speedup vs baseline: 1.1016x; 1.1016x over previous
//
#include <hip/hip_runtime.h>
#include <hip/hip_bf16.h>

#define Bb 8
#define Tt 600
#define Cc 8
#define Ff 257
#define TAPS 5
#define DELAY 3
#define KC 40            // TAPS*C
#define NC 48            // KC + C (R columns | P columns)
#define RPW 53           // RP row stride (float2): 106 dwords, gcd(106,32)=2 -> 16-bank row spread
#define TQ 593           // T - DELAY - TAPS + 1
#define TP 602           // Y LDS row stride (float2): conflict-free for channel-strided access
#define EPSF 1e-10f
#define NTOT (Bb*Tt*Cc*Ff)   // 9,868,800

__device__ __forceinline__ float2 cmul2(float2 a, float2 b) {
  return make_float2(a.x*b.x - a.y*b.y, a.x*b.y + a.y*b.x);
}

// acc += conj(a)*b with a pre-scaled: (ax,ay) = (w*y.x, w*y.y)
#define CMAC(acc, ax, ay, b)                    \
  acc.x = fmaf(ax, b.x, acc.x);                 \
  acc.x = fmaf(ay, b.y, acc.x);                 \
  acc.y = fmaf(ax, b.y, acc.y);                 \
  acc.y = fmaf(-(ay), b.x, acc.y);

// (B,T,C,F) re/im planes -> (B,F,C,T) interleaved float2
__global__ __launch_bounds__(256) void k_tin(const float* __restrict__ in_re,
                                             const float* __restrict__ in_im,
                                             float2* __restrict__ Yt) {
  __shared__ float2 tile[32][33];
  int f0 = blockIdx.x * 32, t0 = blockIdx.y * 32;
  int b = blockIdx.z >> 3, c = blockIdx.z & 7;
  int tx = threadIdx.x & 31, ty = threadIdx.x >> 5;
#pragma unroll
  for (int ii = 0; ii < 4; ++ii) {
    int t = t0 + ty + 8 * ii, f = f0 + tx;
    if (t < Tt && f < Ff) {
      size_t idx = (((size_t)b * Tt + t) * Cc + c) * Ff + f;
      tile[ty + 8 * ii][tx] = make_float2(in_re[idx], in_im[idx]);
    }
  }
  __syncthreads();
#pragma unroll
  for (int ii = 0; ii < 4; ++ii) {
    int f = f0 + ty + 8 * ii, t = t0 + tx;
    if (f < Ff && t < Tt) {
      size_t o = (((size_t)b * Ff + f) * Cc + c) * Tt + t;
      Yt[o] = tile[tx][ty + 8 * ii];
    }
  }
}

// Per-wave accumulation over t in [tA,tB) for an l-subset of the 5x5 tap tile.
// LBASE..LBASE+LN-1 = l (column-tap) range; DOP: also accumulate the 5 P taps.
// Register budget is the point: LN=2 + P  or  LN=3 alone keeps live state
// < 64 VGPRs so the accumulators never round-trip through AGPRs.
template<int LBASE, int LN, bool DOP>
__device__ __forceinline__ void accum_lset(const float2* __restrict__ Yd,
                                           const float2* __restrict__ Ye,
                                           const float* __restrict__ wl,
                                           int tA, int tB,
                                           float2 (&rac)[5][LN],
                                           float2* pac) {
  float2 wd[5], we[5];
#pragma unroll
  for (int i = 0; i < 4; ++i) { wd[i] = Yd[tA + i]; we[i] = Ye[tA + i]; }

  int tb = tA;
  for (; tb + 5 <= tB; tb += 5) {
#pragma unroll
    for (int u = 0; u < 5; ++u) {            // u literal: %5 indices fold
      float2 ynd = Yd[tb + u + 4];
      float2 yne = Ye[tb + u + 4];
      float w = wl[tb + u + 7];
      wd[(u + 4) % 5] = ynd; we[(u + 4) % 5] = yne;
      float ax[5], ay[5];
#pragma unroll
      for (int k = 0; k < 5; ++k) {
        float2 yr = wd[(u + 4 - k) % 5]; ax[k] = w * yr.x; ay[k] = w * yr.y;
      }
#pragma unroll
      for (int j = 0; j < LN; ++j) {
        float2 yc = we[(u + 4 - (LBASE + j)) % 5];
#pragma unroll
        for (int k = 0; k < 5; ++k) { CMAC(rac[k][j], ax[k], ay[k], yc); }
      }
      if constexpr (DOP) {
        float2 yep = Ye[tb + u + 7];
#pragma unroll
        for (int k = 0; k < 5; ++k) { CMAC(pac[k], ax[k], ay[k], yep); }
      }
    }
  }
  for (int t = tb; t < tB; ++t) {            // tail (<=4 iters): fresh reads
    float w = wl[t + 7];
    float ax[5], ay[5];
#pragma unroll
    for (int k = 0; k < 5; ++k) {
      float2 yr = Yd[t + 4 - k]; ax[k] = w * yr.x; ay[k] = w * yr.y;
    }
#pragma unroll
    for (int j = 0; j < LN; ++j) {
      float2 yc = Ye[t + 4 - (LBASE + j)];
#pragma unroll
      for (int k = 0; k < 5; ++k) { CMAC(rac[k][j], ax[k], ay[k], yc); }
    }
    if constexpr (DOP) {
      float2 yep = Ye[t + 7];
#pragma unroll
      for (int k = 0; k < 5; ++k) { CMAC(pac[k], ax[k], ay[k], yep); }
    }
  }
}

// One block (512 thr) per (b,f): full 2-iteration WPE.
// Accumulation: 8 waves = 4 t-groups x 2 l-sets; thread=(d,e) owns a 5x(2|3)
// R-subtile (+5 P taps on lset0) -- per-thread state < 64 VGPRs (no AGPR
// round-trips).  4-pass merge (l-sets write disjoint columns); 1-barrier GJ
// solve.  enh aliases Yt (each block stages its slice to LDS before writing).
__global__ void __launch_bounds__(512, 4)
__attribute__((amdgpu_waves_per_eu(4, 4)))
k_wpe(const float2* __restrict__ Yt,
      float2* __restrict__ enh,
      const float* __restrict__ in_re,
      const float* __restrict__ in_im,
      const int* __restrict__ ilens,
      float* __restrict__ out_re,
      float* __restrict__ out_im,
      int load_direct, int store_direct) {
  __shared__ float2 Yl[Cc][TP];        // 8 x 602 complex = 38528 B
  __shared__ float2 RP[KC][RPW];       // [R | P] 40 x 53      = 16960 B
  __shared__ float wl[Tt];             // 2400 B   -> total 57888 B

  // XCD-chunked bijective swizzle (2056 % 8 == 0): bf = (orig%8)*257 + orig/8
  int orig = blockIdx.x;
  int bf = (orig & 7) * (Bb * Ff / 8) + (orig >> 3);
  int b = bf / Ff, f = bf % Ff;
  int tid = threadIdx.x;               // 0..511
  int group = tid >> 6;                // wave id
  int lane = tid & 63;
  int d = lane & 7;                    // row channel
  int e = lane >> 3;                   // col channel
  int tg = group >> 1;                 // t-group 0..3
  int ls = group & 1;                  // l-set: 0 -> l{0,1}+P, 1 -> l{2,3,4}

  // solve mapping: thread = (row, col-chunk), 480 active
  int srow = tid % KC;                 // const divisor -> magic mul, hoisted
  int scol = tid / KC;                 // 0..12

  // ---- stage Y into LDS
  if (!load_direct) {
    const float4* Yg = (const float4*)(Yt + (size_t)bf * (Cc * Tt));
    for (int i = tid; i < Cc * Tt / 2; i += 512) {
      float4 v = Yg[i];
      int c = i / (Tt / 2), t2 = (i % (Tt / 2)) * 2;
      *(float4*)&Yl[c][t2] = v;        // 16B aligned: 602*c + t2 even
    }
  } else {
    for (int i = tid; i < Cc * Tt; i += 512) {
      int c = i / Tt, t = i % Tt;
      size_t idx = (((size_t)b * Tt + t) * Cc + c) * Ff + f;
      Yl[c][t] = make_float2(in_re[idx], in_im[idx]);
    }
  }
  __syncthreads();

  const float2* Yd = &Yl[d][0];
  const float2* Ye = &Yl[e][0];

  int tA4 = (TQ * tg) >> 2;
  int tB4 = (TQ * (tg + 1)) >> 2;

  for (int iter = 0; iter < 3; ++iter) {
    // ---- weights (iter 0 from Y); iter 1: apply filter -> weights; iter 2: apply -> store
    if (iter == 0) {
      for (int t = tid; t < Tt; t += 512) {
        float s = 0.f;
#pragma unroll
        for (int c = 0; c < Cc; ++c) { float2 y = Yl[c][t]; s += y.x*y.x + y.y*y.y; }
        wl[t] = 1.0f / fmaxf(s * 0.125f, EPSF);
      }
    } else {
      int il = (iter == 2 && store_direct) ? ilens[b] : Tt;
      for (int t = tid; t < Tt; t += 512) {
        float2 acc[Cc];
#pragma unroll
        for (int ee = 0; ee < Cc; ++ee) acc[ee] = Yl[ee][t];
        for (int p = 0; p < TAPS; ++p) {
          int ts = t - DELAY - p;
          if (ts < 0) break;   // zero-padded region
#pragma unroll
          for (int dd = 0; dd < Cc; ++dd) {
            float2 u = Yl[dd][ts];
#pragma unroll
            for (int ee = 0; ee < Cc; ++ee) {
              float2 g = RP[p * Cc + dd][KC + ee];  // uniform addr across wave -> broadcast
              acc[ee].x -= g.x*u.x - g.y*u.y;
              acc[ee].y -= g.x*u.y + g.y*u.x;
            }
          }
        }
        if (iter == 1) {
          float s = 0.f;
#pragma unroll
          for (int ee = 0; ee < Cc; ++ee) s += acc[ee].x*acc[ee].x + acc[ee].y*acc[ee].y;
          wl[t] = 1.0f / fmaxf(s * 0.125f, EPSF);
        } else {
          if (!store_direct) {
            float2* Eg = enh + (size_t)bf * (Cc * Tt);
#pragma unroll
            for (int ee = 0; ee < Cc; ++ee) Eg[ee * Tt + t] = acc[ee];  // own Yt slice
          } else {
            bool live = (t < il);
#pragma unroll
            for (int ee = 0; ee < Cc; ++ee) {
              float2 v = live ? acc[ee] : make_float2(0.f, 0.f);
              size_t idx = (((size_t)b * Tt + t) * Cc + ee) * Ff + f;
              out_re[idx] = v.x;
              out_im[idx] = v.y;
            }
          }
        }
      }
    }
    if (iter == 2) break;
    __syncthreads();   // (A) wl ready; apply-phase G reads done

    // ---- accumulate: l-split register subtiles
    float2 rac2[5][2], pacr[5];          // lset0 state (l = 0,1  + P)
    float2 rac3[5][3];                   // lset1 state (l = 2,3,4)
    if (ls == 0) {
#pragma unroll
      for (int k = 0; k < 5; ++k) {
        rac2[k][0] = make_float2(0.f, 0.f);
        rac2[k][1] = make_float2(0.f, 0.f);
        pacr[k] = make_float2(0.f, 0.f);
      }
      accum_lset<0, 2, true>(Yd, Ye, wl, tA4, tB4, rac2, pacr);
    } else {
#pragma unroll
      for (int k = 0; k < 5; ++k)
#pragma unroll
        for (int j = 0; j < 3; ++j) rac3[k][j] = make_float2(0.f, 0.f);
      accum_lset<2, 3, false>(Yd, Ye, wl, tA4, tB4, rac3, nullptr);
    }

    // ---- merge the 4 t-group partials (both l-sets concurrent: disjoint
    // columns).  Pass 0 WRITES (EPS folded on diagonal); no FP atomics.
    for (int gp = 0; gp < 4; ++gp) {
      if (tg == gp) {
        if (ls == 0) {
          if (gp == 0) {
#pragma unroll
            for (int k = 0; k < 5; ++k) {
#pragma unroll
              for (int j = 0; j < 2; ++j) {
                float2 v = rac2[k][j];
                if (k == j && d == e) v.x += EPSF;
                RP[k*8+d][j*8+e] = v;
              }
              RP[k*8+d][KC+e] = pacr[k];
            }
          } else {
#pragma unroll
            for (int k = 0; k < 5; ++k) {
#pragma unroll
              for (int j = 0; j < 2; ++j) {
                float2 v = RP[k*8+d][j*8+e];
                v.x += rac2[k][j].x; v.y += rac2[k][j].y;
                RP[k*8+d][j*8+e] = v;
              }
              float2 v = RP[k*8+d][KC+e];
              v.x += pacr[k].x; v.y += pacr[k].y;
              RP[k*8+d][KC+e] = v;
            }
          }
        } else {
          if (gp == 0) {
#pragma unroll
            for (int k = 0; k < 5; ++k)
#pragma unroll
              for (int j = 0; j < 3; ++j) {
                float2 v = rac3[k][j];
                if (k == (2 + j) && d == e) v.x += EPSF;
                RP[k*8+d][(2+j)*8+e] = v;
              }
          } else {
#pragma unroll
            for (int k = 0; k < 5; ++k)
#pragma unroll
              for (int j = 0; j < 3; ++j) {
                float2 v = RP[k*8+d][(2+j)*8+e];
                v.x += rac3[k][j].x; v.y += rac3[k][j].y;
                RP[k*8+d][(2+j)*8+e] = v;
              }
          }
        }
      }
      __syncthreads();
    }

    // ---- unnormalized Gauss-Jordan on [R | P]: ONE barrier per step.
    // Step j: rows i!=j:  RP[i][k] -= (RP[i][j]/RP[j][j]) * RP[j][k], k>j.
    // Row j and column j are never written during step j -> no intra-step hazard.
    for (int j = 0; j < KC; ++j) {
      if (tid < 480 && srow != j) {
        float2 pv = RP[j][j];
        float idn = 1.0f / (pv.x*pv.x + pv.y*pv.y);
        float2 lij = RP[srow][j];
        float2 fij = make_float2((lij.x*pv.x + lij.y*pv.y) * idn,
                                 (lij.y*pv.x - lij.x*pv.y) * idn);
        for (int k = j + 1 + scol; k < NC; k += 12) {
          float2 c = RP[j][k];
          float sx = fij.x*c.x - fij.y*c.y;
          float sy = fij.x*c.y + fij.y*c.x;
          RP[srow][k].x -= sx;
          RP[srow][k].y -= sy;
        }
      }
      __syncthreads();
    }
    // R is now diagonal; X = R^-1 P obtained by scaling P-columns by 1/diag
    if (tid < KC * Cc) {               // 320 entries
      int i = tid >> 3, ee = tid & 7;
      float2 pv = RP[i][i];
      float idn = 1.0f / (pv.x*pv.x + pv.y*pv.y);
      float2 p2 = RP[i][KC + ee];
      RP[i][KC + ee] = make_float2((p2.x*pv.x + p2.y*pv.y) * idn,
                                   (p2.y*pv.x - p2.x*pv.y) * idn);
    }
    __syncthreads();
  }
}

// (B,F,C,T) float2 -> masked (B,T,C,F) re/im planes
__global__ __launch_bounds__(256) void k_tout(const float2* __restrict__ enh,
                                              const int* __restrict__ ilens,
                                              float* __restrict__ out_re,
                                              float* __restrict__ out_im) {
  __shared__ float2 tile[32][33];
  int t0 = blockIdx.x * 32, f0 = blockIdx.y * 32;
  int b = blockIdx.z >> 3, c = blockIdx.z & 7;
  int tx = threadIdx.x & 31, ty = threadIdx.x >> 5;
#pragma unroll
  for (int ii = 0; ii < 4; ++ii) {
    int f = f0 + ty + 8 * ii, t = t0 + tx;
    if (f < Ff && t < Tt)
      tile[ty + 8 * ii][tx] = enh[(((size_t)b * Ff + f) * Cc + c) * Tt + t];
  }
  __syncthreads();
  int il = ilens[b];
#pragma unroll
  for (int ii = 0; ii < 4; ++ii) {
    int t = t0 + ty + 8 * ii, f = f0 + tx;
    if (t < Tt && f < Ff) {
      float2 v = tile[tx][ty + 8 * ii];
      if (t >= il) v = make_float2(0.f, 0.f);
      size_t idx = (((size_t)b * Tt + t) * Cc + c) * Ff + f;
      out_re[idx] = v.x;
      out_im[idx] = v.y;
    }
  }
}

extern "C" void kernel_launch(void* const* d_in, const int* in_sizes, int n_in,
                              void* d_out, int out_size, void* d_ws, size_t ws_size,
                              hipStream_t stream) {
  const float* in_re = (const float*)d_in[0];
  const float* in_im = (const float*)d_in[1];
  const int* ilens = (const int*)d_in[2];
  float* out_re = (float*)d_out;
  float* out_im = out_re + NTOT;

  size_t ybytes = (size_t)Bb * Ff * Cc * Tt * sizeof(float2);  // 78,950,400 B
  int have_yt = ws_size >= ybytes;
  // enh ALIASES Yt: k_wpe block bf stages Yt[bf] into LDS before writing enh[bf],
  // and no block touches another block's slice -> race-free, halves ws need.
  float2* Yt  = (float2*)d_ws;
  float2* enh = (float2*)d_ws;

  if (have_yt) {
    dim3 g((Ff + 31) / 32, (Tt + 31) / 32, Bb * Cc);
    k_tin<<<g, dim3(256), 0, stream>>>(in_re, in_im, Yt);
  }
  {
    dim3 g(Bb * Ff);
    k_wpe<<<g, dim3(512), 0, stream>>>(Yt, enh, in_re, in_im, ilens,
                                       out_re, out_im,
                                       have_yt ? 0 : 1, have_yt ? 0 : 1);
  }
  if (have_yt) {
    dim3 g((Tt + 31) / 32, (Ff + 31) / 32, Bb * Cc);
    k_tout<<<g, dim3(256), 0, stream>>>(enh, ilens, out_re, out_im);
  }
}

// Round 7
// 844.299 us; speedup vs baseline: 1.3496x; 1.2251x over previous
//
#include <hip/hip_runtime.h>
#include <hip/hip_bf16.h>

#define Bb 8
#define Tt 600
#define Cc 8
#define Ff 257
#define TAPS 5
#define DELAY 3
#define KC 40            // TAPS*C
#define NC 48            // KC + C (R columns | P columns)
#define RPW 53           // RP row stride (float2): 106 dwords, gcd(106,32)=2 -> 16-bank row spread
#define TQ 593           // T - DELAY - TAPS + 1
#define TP 602           // Y LDS row stride (float2): conflict-free for channel-strided access
#define EPSF 1e-10f
#define NTOT (Bb*Tt*Cc*Ff)   // 9,868,800

__device__ __forceinline__ float2 cmul2(float2 a, float2 b) {
  return make_float2(a.x*b.x - a.y*b.y, a.x*b.y + a.y*b.x);
}

// acc += conj(a)*b with a pre-scaled: (ax,ay) = (w*y.x, w*y.y)
#define CMAC(acc, ax, ay, b)                    \
  acc.x = fmaf(ax, b.x, acc.x);                 \
  acc.x = fmaf(ay, b.y, acc.x);                 \
  acc.y = fmaf(ax, b.y, acc.y);                 \
  acc.y = fmaf(-(ay), b.x, acc.y);

// (B,T,C,F) re/im planes -> (B,F,C,T) interleaved float2
__global__ __launch_bounds__(256) void k_tin(const float* __restrict__ in_re,
                                             const float* __restrict__ in_im,
                                             float2* __restrict__ Yt) {
  __shared__ float2 tile[32][33];
  int f0 = blockIdx.x * 32, t0 = blockIdx.y * 32;
  int b = blockIdx.z >> 3, c = blockIdx.z & 7;
  int tx = threadIdx.x & 31, ty = threadIdx.x >> 5;
#pragma unroll
  for (int ii = 0; ii < 4; ++ii) {
    int t = t0 + ty + 8 * ii, f = f0 + tx;
    if (t < Tt && f < Ff) {
      size_t idx = (((size_t)b * Tt + t) * Cc + c) * Ff + f;
      tile[ty + 8 * ii][tx] = make_float2(in_re[idx], in_im[idx]);
    }
  }
  __syncthreads();
#pragma unroll
  for (int ii = 0; ii < 4; ++ii) {
    int f = f0 + ty + 8 * ii, t = t0 + tx;
    if (f < Ff && t < Tt) {
      size_t o = (((size_t)b * Ff + f) * Cc + c) * Tt + t;
      Yt[o] = tile[tx][ty + 8 * ii];
    }
  }
}

// Hermitian split of the 5x5 tap-block grid: R[J][I] = conj(R[I][J]) because
// the weight w(t) is real.  Only the lower triangle is accumulated:
//   wave A (S=0): off-diag blocks {(1,0),(2,0),(3,0),(4,0),(2,1)} + all 5 P taps
//   wave B (S=1): off-diag blocks {(3,1),(4,1),(3,2),(4,2),(4,3)} + diag (k,k)
// 10 CMACs/t per wave (balanced), live state ~50 floats < 64 VGPRs.
template<int S> struct KLSel {
  static constexpr int K[5] = {1,2,3,4,2}, L[5] = {0,0,0,0,1};
};
template<> struct KLSel<1> {
  static constexpr int K[5] = {3,4,3,4,4}, L[5] = {1,1,2,2,3};
};

template<int S>
__device__ __forceinline__ void accum_herm(const float2* __restrict__ Yd,
                                           const float2* __restrict__ Ye,
                                           const float* __restrict__ wl,
                                           int tA, int tB,
                                           float2 (&rko)[5], float2 (&rp5)[5]) {
  using KL = KLSel<S>;
  float2 wd[5], we[5];
#pragma unroll
  for (int i = 0; i < 4; ++i) { wd[i] = Yd[tA + i]; we[i] = Ye[tA + i]; }

  int tb = tA;
  for (; tb + 5 <= tB; tb += 5) {
#pragma unroll
    for (int u = 0; u < 5; ++u) {            // u literal: %5 indices fold
      float2 ynd = Yd[tb + u + 4];
      float2 yne = Ye[tb + u + 4];
      float w = wl[tb + u + 7];
      wd[(u + 4) % 5] = ynd; we[(u + 4) % 5] = yne;
      float ax[5], ay[5];
#pragma unroll
      for (int k = 0; k < 5; ++k) {
        float2 yr = wd[(u + 4 - k) % 5]; ax[k] = w * yr.x; ay[k] = w * yr.y;
      }
#pragma unroll
      for (int j = 0; j < 5; ++j) {
        float2 yc = we[(u + 4 - KL::L[j]) % 5];
        CMAC(rko[j], ax[KL::K[j]], ay[KL::K[j]], yc);
      }
      if constexpr (S == 0) {
        float2 yep = Ye[tb + u + 7];
#pragma unroll
        for (int k = 0; k < 5; ++k) { CMAC(rp5[k], ax[k], ay[k], yep); }
      } else {
#pragma unroll
        for (int k = 0; k < 5; ++k) {        // diagonal blocks (k,k)
          float2 yc = we[(u + 4 - k) % 5];
          CMAC(rp5[k], ax[k], ay[k], yc);
        }
      }
    }
  }
  for (int t = tb; t < tB; ++t) {            // tail (<=4 iters): fresh reads
    float w = wl[t + 7];
    float ax[5], ay[5];
#pragma unroll
    for (int k = 0; k < 5; ++k) {
      float2 yr = Yd[t + 4 - k]; ax[k] = w * yr.x; ay[k] = w * yr.y;
    }
#pragma unroll
    for (int j = 0; j < 5; ++j) {
      float2 yc = Ye[t + 4 - KL::L[j]];
      CMAC(rko[j], ax[KL::K[j]], ay[KL::K[j]], yc);
    }
    if constexpr (S == 0) {
      float2 yep = Ye[t + 7];
#pragma unroll
      for (int k = 0; k < 5; ++k) { CMAC(rp5[k], ax[k], ay[k], yep); }
    } else {
#pragma unroll
      for (int k = 0; k < 5; ++k) {
        float2 yc = Ye[t + 4 - k];
        CMAC(rp5[k], ax[k], ay[k], yc);
      }
    }
  }
}

// One block (512 thr) per (b,f): full 2-iteration WPE.
// Accumulation: 8 waves = 4 t-groups x 2 Hermitian half-sets (lower-triangle
// only, -33% CMACs); 4-pass merge; conj-reconstruct of the upper triangle;
// 1-barrier GJ solve.  enh aliases Yt.
__global__ void __launch_bounds__(512, 4)
__attribute__((amdgpu_waves_per_eu(4, 4)))
k_wpe(const float2* __restrict__ Yt,
      float2* __restrict__ enh,
      const float* __restrict__ in_re,
      const float* __restrict__ in_im,
      const int* __restrict__ ilens,
      float* __restrict__ out_re,
      float* __restrict__ out_im,
      int load_direct, int store_direct) {
  __shared__ float2 Yl[Cc][TP];        // 8 x 602 complex = 38528 B
  __shared__ float2 RP[KC][RPW];       // [R | P] 40 x 53      = 16960 B
  __shared__ float wl[Tt];             // 2400 B   -> total 57888 B

  // XCD-chunked bijective swizzle (2056 % 8 == 0): bf = (orig%8)*257 + orig/8
  int orig = blockIdx.x;
  int bf = (orig & 7) * (Bb * Ff / 8) + (orig >> 3);
  int b = bf / Ff, f = bf % Ff;
  int tid = threadIdx.x;               // 0..511
  int group = tid >> 6;                // wave id
  int lane = tid & 63;
  int d = lane & 7;                    // row channel
  int e = lane >> 3;                   // col channel
  int tg = group >> 1;                 // t-group 0..3
  int ls = group & 1;                  // half-set: 0 -> A(+P), 1 -> B(+diag)

  // solve mapping: thread = (row, col-chunk), 480 active
  int srow = tid % KC;                 // const divisor -> magic mul, hoisted
  int scol = tid / KC;                 // 0..12

  // ---- stage Y into LDS
  if (!load_direct) {
    const float4* Yg = (const float4*)(Yt + (size_t)bf * (Cc * Tt));
    for (int i = tid; i < Cc * Tt / 2; i += 512) {
      float4 v = Yg[i];
      int c = i / (Tt / 2), t2 = (i % (Tt / 2)) * 2;
      *(float4*)&Yl[c][t2] = v;        // 16B aligned: 602*c + t2 even
    }
  } else {
    for (int i = tid; i < Cc * Tt; i += 512) {
      int c = i / Tt, t = i % Tt;
      size_t idx = (((size_t)b * Tt + t) * Cc + c) * Ff + f;
      Yl[c][t] = make_float2(in_re[idx], in_im[idx]);
    }
  }
  __syncthreads();

  const float2* Yd = &Yl[d][0];
  const float2* Ye = &Yl[e][0];

  int tA4 = (TQ * tg) >> 2;
  int tB4 = (TQ * (tg + 1)) >> 2;

  for (int iter = 0; iter < 3; ++iter) {
    // ---- weights (iter 0 from Y); iter 1: apply filter -> weights; iter 2: apply -> store
    if (iter == 0) {
      for (int t = tid; t < Tt; t += 512) {
        float s = 0.f;
#pragma unroll
        for (int c = 0; c < Cc; ++c) { float2 y = Yl[c][t]; s += y.x*y.x + y.y*y.y; }
        wl[t] = 1.0f / fmaxf(s * 0.125f, EPSF);
      }
    } else {
      int il = (iter == 2 && store_direct) ? ilens[b] : Tt;
      for (int t = tid; t < Tt; t += 512) {
        float2 acc[Cc];
#pragma unroll
        for (int ee = 0; ee < Cc; ++ee) acc[ee] = Yl[ee][t];
        for (int p = 0; p < TAPS; ++p) {
          int ts = t - DELAY - p;
          if (ts < 0) break;   // zero-padded region
#pragma unroll
          for (int dd = 0; dd < Cc; ++dd) {
            float2 u = Yl[dd][ts];
#pragma unroll
            for (int ee = 0; ee < Cc; ++ee) {
              float2 g = RP[p * Cc + dd][KC + ee];  // uniform addr across wave -> broadcast
              acc[ee].x -= g.x*u.x - g.y*u.y;
              acc[ee].y -= g.x*u.y + g.y*u.x;
            }
          }
        }
        if (iter == 1) {
          float s = 0.f;
#pragma unroll
          for (int ee = 0; ee < Cc; ++ee) s += acc[ee].x*acc[ee].x + acc[ee].y*acc[ee].y;
          wl[t] = 1.0f / fmaxf(s * 0.125f, EPSF);
        } else {
          if (!store_direct) {
            float2* Eg = enh + (size_t)bf * (Cc * Tt);
#pragma unroll
            for (int ee = 0; ee < Cc; ++ee) Eg[ee * Tt + t] = acc[ee];  // own Yt slice
          } else {
            bool live = (t < il);
#pragma unroll
            for (int ee = 0; ee < Cc; ++ee) {
              float2 v = live ? acc[ee] : make_float2(0.f, 0.f);
              size_t idx = (((size_t)b * Tt + t) * Cc + ee) * Ff + f;
              out_re[idx] = v.x;
              out_im[idx] = v.y;
            }
          }
        }
      }
    }
    if (iter == 2) break;
    __syncthreads();   // (A) wl ready; apply-phase G reads done

    // ---- accumulate: Hermitian lower-triangle register subtiles
    float2 rko[5], rp5[5];
#pragma unroll
    for (int k = 0; k < 5; ++k) {
      rko[k] = make_float2(0.f, 0.f);
      rp5[k] = make_float2(0.f, 0.f);
    }
    if (ls == 0) accum_herm<0>(Yd, Ye, wl, tA4, tB4, rko, rp5);
    else         accum_herm<1>(Yd, Ye, wl, tA4, tB4, rko, rp5);

    // ---- merge the 4 t-group partials (half-sets write disjoint regions).
    // Pass 0 WRITES (EPS folded onto the diagonal); no FP atomics.
    for (int gp = 0; gp < 4; ++gp) {
      if (tg == gp) {
        if (ls == 0) {
          if (gp == 0) {
#pragma unroll
            for (int j = 0; j < 5; ++j)
              RP[KLSel<0>::K[j]*8+d][KLSel<0>::L[j]*8+e] = rko[j];
#pragma unroll
            for (int k = 0; k < 5; ++k) RP[k*8+d][KC+e] = rp5[k];
          } else {
#pragma unroll
            for (int j = 0; j < 5; ++j) {
              float2 v = RP[KLSel<0>::K[j]*8+d][KLSel<0>::L[j]*8+e];
              v.x += rko[j].x; v.y += rko[j].y;
              RP[KLSel<0>::K[j]*8+d][KLSel<0>::L[j]*8+e] = v;
            }
#pragma unroll
            for (int k = 0; k < 5; ++k) {
              float2 v = RP[k*8+d][KC+e];
              v.x += rp5[k].x; v.y += rp5[k].y;
              RP[k*8+d][KC+e] = v;
            }
          }
        } else {
          if (gp == 0) {
#pragma unroll
            for (int j = 0; j < 5; ++j)
              RP[KLSel<1>::K[j]*8+d][KLSel<1>::L[j]*8+e] = rko[j];
            if (d >= e) {
#pragma unroll
              for (int k = 0; k < 5; ++k) {
                float2 v = rp5[k];
                if (d == e) v.x += EPSF;
                RP[k*8+d][k*8+e] = v;
              }
            }
          } else {
#pragma unroll
            for (int j = 0; j < 5; ++j) {
              float2 v = RP[KLSel<1>::K[j]*8+d][KLSel<1>::L[j]*8+e];
              v.x += rko[j].x; v.y += rko[j].y;
              RP[KLSel<1>::K[j]*8+d][KLSel<1>::L[j]*8+e] = v;
            }
            if (d >= e) {
#pragma unroll
              for (int k = 0; k < 5; ++k) {
                float2 v = RP[k*8+d][k*8+e];
                v.x += rp5[k].x; v.y += rp5[k].y;
                RP[k*8+d][k*8+e] = v;
              }
            }
          }
        }
      }
      __syncthreads();
    }

    // ---- reconstruct the upper triangle: R[I][J] = conj(R[J][I]) for I<J
    for (int idx = tid; idx < KC * KC; idx += 512) {
      int I = idx / KC, J = idx - I * KC;    // const divisor -> magic mul
      if (I < J) {
        float2 v = RP[J][I];
        RP[I][J] = make_float2(v.x, -v.y);
      }
    }
    __syncthreads();

    // ---- unnormalized Gauss-Jordan on [R | P]: ONE barrier per step.
    // Step j: rows i!=j:  RP[i][k] -= (RP[i][j]/RP[j][j]) * RP[j][k], k>j.
    // Row j and column j are never written during step j -> no intra-step hazard.
    for (int j = 0; j < KC; ++j) {
      if (tid < 480 && srow != j) {
        float2 pv = RP[j][j];
        float idn = 1.0f / (pv.x*pv.x + pv.y*pv.y);
        float2 lij = RP[srow][j];
        float2 fij = make_float2((lij.x*pv.x + lij.y*pv.y) * idn,
                                 (lij.y*pv.x - lij.x*pv.y) * idn);
        for (int k = j + 1 + scol; k < NC; k += 12) {
          float2 c = RP[j][k];
          float sx = fij.x*c.x - fij.y*c.y;
          float sy = fij.x*c.y + fij.y*c.x;
          RP[srow][k].x -= sx;
          RP[srow][k].y -= sy;
        }
      }
      __syncthreads();
    }
    // R is now diagonal; X = R^-1 P obtained by scaling P-columns by 1/diag
    if (tid < KC * Cc) {               // 320 entries
      int i = tid >> 3, ee = tid & 7;
      float2 pv = RP[i][i];
      float idn = 1.0f / (pv.x*pv.x + pv.y*pv.y);
      float2 p2 = RP[i][KC + ee];
      RP[i][KC + ee] = make_float2((p2.x*pv.x + p2.y*pv.y) * idn,
                                   (p2.y*pv.x - p2.x*pv.y) * idn);
    }
    __syncthreads();
  }
}

// (B,F,C,T) float2 -> masked (B,T,C,F) re/im planes
__global__ __launch_bounds__(256) void k_tout(const float2* __restrict__ enh,
                                              const int* __restrict__ ilens,
                                              float* __restrict__ out_re,
                                              float* __restrict__ out_im) {
  __shared__ float2 tile[32][33];
  int t0 = blockIdx.x * 32, f0 = blockIdx.y * 32;
  int b = blockIdx.z >> 3, c = blockIdx.z & 7;
  int tx = threadIdx.x & 31, ty = threadIdx.x >> 5;
#pragma unroll
  for (int ii = 0; ii < 4; ++ii) {
    int f = f0 + ty + 8 * ii, t = t0 + tx;
    if (f < Ff && t < Tt)
      tile[ty + 8 * ii][tx] = enh[(((size_t)b * Ff + f) * Cc + c) * Tt + t];
  }
  __syncthreads();
  int il = ilens[b];
#pragma unroll
  for (int ii = 0; ii < 4; ++ii) {
    int t = t0 + ty + 8 * ii, f = f0 + tx;
    if (t < Tt && f < Ff) {
      float2 v = tile[tx][ty + 8 * ii];
      if (t >= il) v = make_float2(0.f, 0.f);
      size_t idx = (((size_t)b * Tt + t) * Cc + c) * Ff + f;
      out_re[idx] = v.x;
      out_im[idx] = v.y;
    }
  }
}

extern "C" void kernel_launch(void* const* d_in, const int* in_sizes, int n_in,
                              void* d_out, int out_size, void* d_ws, size_t ws_size,
                              hipStream_t stream) {
  const float* in_re = (const float*)d_in[0];
  const float* in_im = (const float*)d_in[1];
  const int* ilens = (const int*)d_in[2];
  float* out_re = (float*)d_out;
  float* out_im = out_re + NTOT;

  size_t ybytes = (size_t)Bb * Ff * Cc * Tt * sizeof(float2);  // 78,950,400 B
  int have_yt = ws_size >= ybytes;
  // enh ALIASES Yt: k_wpe block bf stages Yt[bf] into LDS before writing enh[bf],
  // and no block touches another block's slice -> race-free, halves ws need.
  float2* Yt  = (float2*)d_ws;
  float2* enh = (float2*)d_ws;

  if (have_yt) {
    dim3 g((Ff + 31) / 32, (Tt + 31) / 32, Bb * Cc);
    k_tin<<<g, dim3(256), 0, stream>>>(in_re, in_im, Yt);
  }
  {
    dim3 g(Bb * Ff);
    k_wpe<<<g, dim3(512), 0, stream>>>(Yt, enh, in_re, in_im, ilens,
                                       out_re, out_im,
                                       have_yt ? 0 : 1, have_yt ? 0 : 1);
  }
  if (have_yt) {
    dim3 g((Tt + 31) / 32, (Ff + 31) / 32, Bb * Cc);
    k_tout<<<g, dim3(256), 0, stream>>>(enh, ilens, out_re, out_im);
  }
}

// Round 8
// 816.192 us; speedup vs baseline: 1.3961x; 1.0344x over previous
//
#include <hip/hip_runtime.h>
#include <hip/hip_bf16.h>

#define Bb 8
#define Tt 600
#define Cc 8
#define Ff 257
#define TAPS 5
#define DELAY 3
#define KC 40            // TAPS*C
#define NC 48            // KC + C (R columns | P columns)
#define RPW 53           // RP row stride (float2): 106 dw, gcd(106,32)=2 -> 16-bank row spread
#define TQ 593           // T - DELAY - TAPS + 1
#define TP 606           // Yl row stride (float2): 1212 dw -> d*28%32 all-distinct, conflict-free
#define WLN 608          // wl with zero pads [600..607]
#define AEND 597         // TQ + 4: lag-product a-range
#define EPSF 1e-10f
#define NTOT (Bb*Tt*Cc*Ff)   // 9,868,800

// Lower-triangle tap-block tables: id -> (k,l), grouped by lag tau=k-l.
constexpr int kABASE[5] = {0, 5, 9, 12, 14};
constexpr int kK15[15] = {0,1,2,3,4, 1,2,3,4, 2,3,4, 3,4, 4};
constexpr int kL15[15] = {0,1,2,3,4, 0,1,2,3, 0,1,2, 0,1, 0};

// (B,T,C,F) re/im planes -> (B,F,C,T) interleaved float2
__global__ __launch_bounds__(256) void k_tin(const float* __restrict__ in_re,
                                             const float* __restrict__ in_im,
                                             float2* __restrict__ Yt) {
  __shared__ float2 tile[32][33];
  int f0 = blockIdx.x * 32, t0 = blockIdx.y * 32;
  int b = blockIdx.z >> 3, c = blockIdx.z & 7;
  int tx = threadIdx.x & 31, ty = threadIdx.x >> 5;
#pragma unroll
  for (int ii = 0; ii < 4; ++ii) {
    int t = t0 + ty + 8 * ii, f = f0 + tx;
    if (t < Tt && f < Ff) {
      size_t idx = (((size_t)b * Tt + t) * Cc + c) * Ff + f;
      tile[ty + 8 * ii][tx] = make_float2(in_re[idx], in_im[idx]);
    }
  }
  __syncthreads();
#pragma unroll
  for (int ii = 0; ii < 4; ++ii) {
    int f = f0 + ty + 8 * ii, t = t0 + tx;
    if (f < Ff && t < Tt) {
      size_t o = (((size_t)b * Ff + f) * Cc + c) * Tt + t;
      Yt[o] = tile[tx][ty + 8 * ii];
    }
  }
}

// Lag-product accumulation step (u literal 0..7; ring slots fold to constants).
// p_tau(a) = conj(Yd[a])*Ye[a+tau] shared across all blocks of lag tau:
//   R[k][k-tau] += wl[a+3+k] * p_tau(a)   (w real -> 2 FMA per block)
//   P[tau-3]    += wl[a+tau] * p_tau(a)   (tau = 3..7)
// Zero-padded wl ([0..6] and [600..607]) makes per-k range ends vanish.
#define ASTEP(u) do {                                                     \
  int a_ = aA + i + (u);                                                  \
  float2 yd_ = Yd[a_];                                                    \
  ye[((u) + 7) & 7] = Ye[a_ + 7];                                         \
  w8[((u) + 7) & 7] = wl[a_ + 7];                                         \
  _Pragma("unroll")                                                       \
  for (int tau_ = 0; tau_ < 8; ++tau_) {                                  \
    float2 yv_ = ye[((u) + tau_) & 7];                                    \
    float px_ = fmaf(yd_.y, yv_.y, yd_.x * yv_.x);                        \
    float py_ = fmaf(yd_.x, yv_.y, -(yd_.y * yv_.x));                     \
    if (tau_ <= 4) {                                                      \
      _Pragma("unroll")                                                   \
      for (int k_ = tau_; k_ < 5; ++k_) {                                 \
        float wk_ = w8[((u) + 3 + k_) & 7];                               \
        int id_ = kABASE[tau_] + (k_ - tau_);                             \
        rac[id_].x = fmaf(wk_, px_, rac[id_].x);                          \
        rac[id_].y = fmaf(wk_, py_, rac[id_].y);                          \
      }                                                                   \
    }                                                                     \
    if (tau_ >= 3) {                                                      \
      float wk_ = w8[((u) + tau_) & 7];                                   \
      pac[tau_ - 3].x = fmaf(wk_, px_, pac[tau_ - 3].x);                  \
      pac[tau_ - 3].y = fmaf(wk_, py_, pac[tau_ - 3].y);                  \
    }                                                                     \
  }                                                                       \
} while (0)

// One block (512 thr) per (b,f): full 2-iteration WPE.
// Accumulation: 8 waves = 8 a-groups; each thread (d,e) owns the FULL
// lower-triangle 15 R-blocks + 5 P via shared lag-products (72 FMA/a vs 100).
// Needs ~76 live VGPRs -> launch_bounds(512,4) grants 128 (LDS caps at 2
// blocks/CU anyway).  8-pass merge; conj-reconstruct; 1-barrier GJ solve.
// enh aliases Yt.
__global__ void __launch_bounds__(512, 4)
__attribute__((amdgpu_waves_per_eu(4, 4)))
k_wpe(const float2* __restrict__ Yt,
      float2* __restrict__ enh,
      const float* __restrict__ in_re,
      const float* __restrict__ in_im,
      const int* __restrict__ ilens,
      float* __restrict__ out_re,
      float* __restrict__ out_im,
      int load_direct, int store_direct) {
  __shared__ float2 Yl[Cc][TP];        // 8 x 606 complex = 38784 B
  __shared__ float2 RP[KC][RPW];       // [R | P] 40 x 53  = 16960 B
  __shared__ float wl[WLN];            // 2432 B  -> total 58176 B

  // XCD-chunked bijective swizzle (2056 % 8 == 0): bf = (orig%8)*257 + orig/8
  int orig = blockIdx.x;
  int bf = (orig & 7) * (Bb * Ff / 8) + (orig >> 3);
  int b = bf / Ff, f = bf % Ff;
  int tid = threadIdx.x;               // 0..511
  int group = tid >> 6;                // wave id = a-group 0..7
  int lane = tid & 63;
  int d = lane & 7;                    // row channel
  int e = lane >> 3;                   // col channel

  // solve mapping: thread = (row, col-chunk), 480 active
  int srow = tid % KC;                 // const divisor -> magic mul, hoisted
  int scol = tid / KC;                 // 0..12

  // ---- stage Y into LDS (+ zero pads enabling the maskless lag loop)
  if (tid < 8) wl[600 + tid] = 0.f;
  if (tid < 48) { int c = tid / 6; Yl[c][600 + tid % 6] = make_float2(0.f, 0.f); }
  if (!load_direct) {
    const float4* Yg = (const float4*)(Yt + (size_t)bf * (Cc * Tt));
    for (int i = tid; i < Cc * Tt / 2; i += 512) {
      float4 v = Yg[i];
      int c = i / (Tt / 2), t2 = (i % (Tt / 2)) * 2;
      *(float4*)&Yl[c][t2] = v;        // 16B aligned: 606*c + t2 even
    }
  } else {
    for (int i = tid; i < Cc * Tt; i += 512) {
      int c = i / Tt, t = i % Tt;
      size_t idx = (((size_t)b * Tt + t) * Cc + c) * Ff + f;
      Yl[c][t] = make_float2(in_re[idx], in_im[idx]);
    }
  }
  __syncthreads();

  const float2* Yd = &Yl[d][0];
  const float2* Ye = &Yl[e][0];

  for (int iter = 0; iter < 3; ++iter) {
    // ---- weights (iter 0 from Y); iter 1: apply filter -> weights; iter 2: apply -> store
    // wl[t<7] forced to 0: unused by the weights' consumers, required as the
    // zero pad of the lag-product loop.
    if (iter == 0) {
      for (int t = tid; t < Tt; t += 512) {
        float s = 0.f;
#pragma unroll
        for (int c = 0; c < Cc; ++c) { float2 y = Yl[c][t]; s += y.x*y.x + y.y*y.y; }
        wl[t] = (t < 7) ? 0.f : 1.0f / fmaxf(s * 0.125f, EPSF);
      }
    } else {
      int il = (iter == 2 && store_direct) ? ilens[b] : Tt;
      for (int t = tid; t < Tt; t += 512) {
        float2 acc[Cc];
#pragma unroll
        for (int ee = 0; ee < Cc; ++ee) acc[ee] = Yl[ee][t];
        for (int p = 0; p < TAPS; ++p) {
          int ts = t - DELAY - p;
          if (ts < 0) break;   // zero-padded region
#pragma unroll
          for (int dd = 0; dd < Cc; ++dd) {
            float2 u = Yl[dd][ts];
#pragma unroll
            for (int ee = 0; ee < Cc; ++ee) {
              float2 g = RP[p * Cc + dd][KC + ee];  // uniform addr across wave -> broadcast
              acc[ee].x -= g.x*u.x - g.y*u.y;
              acc[ee].y -= g.x*u.y + g.y*u.x;
            }
          }
        }
        if (iter == 1) {
          float s = 0.f;
#pragma unroll
          for (int ee = 0; ee < Cc; ++ee) s += acc[ee].x*acc[ee].x + acc[ee].y*acc[ee].y;
          wl[t] = (t < 7) ? 0.f : 1.0f / fmaxf(s * 0.125f, EPSF);
        } else {
          if (!store_direct) {
            float2* Eg = enh + (size_t)bf * (Cc * Tt);
#pragma unroll
            for (int ee = 0; ee < Cc; ++ee) Eg[ee * Tt + t] = acc[ee];  // own Yt slice
          } else {
            bool live = (t < il);
#pragma unroll
            for (int ee = 0; ee < Cc; ++ee) {
              float2 v = live ? acc[ee] : make_float2(0.f, 0.f);
              size_t idx = (((size_t)b * Tt + t) * Cc + ee) * Ff + f;
              out_re[idx] = v.x;
              out_im[idx] = v.y;
            }
          }
        }
      }
    }
    if (iter == 2) break;
    __syncthreads();   // (A) wl ready; apply-phase G reads done

    // ---- accumulate: full lower triangle + P per thread, lag-product form
    float2 rac[15], pac[5];
#pragma unroll
    for (int j = 0; j < 15; ++j) rac[j] = make_float2(0.f, 0.f);
#pragma unroll
    for (int j = 0; j < 5; ++j) pac[j] = make_float2(0.f, 0.f);

    {
      int aA = (AEND * group) >> 3;
      int aB = (AEND * (group + 1)) >> 3;
      float2 ye[8]; float w8[8];
#pragma unroll
      for (int j = 0; j < 7; ++j) ye[j & 7] = Ye[aA + j];
#pragma unroll
      for (int j = 0; j < 4; ++j) w8[(3 + j) & 7] = wl[aA + 3 + j];
      int len = aB - aA;
      int i = 0;
      for (; i + 8 <= len; i += 8) {
        ASTEP(0); ASTEP(1); ASTEP(2); ASTEP(3);
        ASTEP(4); ASTEP(5); ASTEP(6); ASTEP(7);
      }
      for (; i < len; ++i) {             // tail <=7: direct LDS reads
        int a = aA + i;
        float2 yd = Yd[a];
#pragma unroll
        for (int tau = 0; tau < 8; ++tau) {
          float2 yv = Ye[a + tau];
          float px = fmaf(yd.y, yv.y, yd.x * yv.x);
          float py = fmaf(yd.x, yv.y, -(yd.y * yv.x));
          if (tau <= 4) {
#pragma unroll
            for (int k = tau; k < 5; ++k) {
              float wk = wl[a + 3 + k];
              int id = kABASE[tau] + (k - tau);
              rac[id].x = fmaf(wk, px, rac[id].x);
              rac[id].y = fmaf(wk, py, rac[id].y);
            }
          }
          if (tau >= 3) {
            float wk = wl[a + tau];
            pac[tau - 3].x = fmaf(wk, px, pac[tau - 3].x);
            pac[tau - 3].y = fmaf(wk, py, pac[tau - 3].y);
          }
        }
      }
    }

    // ---- merge the 8 a-group partials (sequential wave passes; pass 0
    // writes, EPS folded onto the diagonal; no FP atomics).
    for (int gpass = 0; gpass < 8; ++gpass) {
      if (group == gpass) {
        if (gpass == 0) {
#pragma unroll
          for (int id = 0; id < 15; ++id) {
            float2 v = rac[id];
            if (id < 5 && d == e) v.x += EPSF;   // ids 0..4 are diag blocks
            RP[kK15[id]*8 + d][kL15[id]*8 + e] = v;
          }
#pragma unroll
          for (int k = 0; k < 5; ++k) RP[k*8 + d][KC + e] = pac[k];
        } else {
#pragma unroll
          for (int id = 0; id < 15; ++id) {
            float2 v = RP[kK15[id]*8 + d][kL15[id]*8 + e];
            v.x += rac[id].x; v.y += rac[id].y;
            RP[kK15[id]*8 + d][kL15[id]*8 + e] = v;
          }
#pragma unroll
          for (int k = 0; k < 5; ++k) {
            float2 v = RP[k*8 + d][KC + e];
            v.x += pac[k].x; v.y += pac[k].y;
            RP[k*8 + d][KC + e] = v;
          }
        }
      }
      __syncthreads();
    }

    // ---- reconstruct the upper triangle: R[I][J] = conj(R[J][I]) for I<J
    // (diag-block upper halves get overwritten with their exact conjugates)
    for (int idx = tid; idx < KC * KC; idx += 512) {
      int I = idx / KC, J = idx - I * KC;    // const divisor -> magic mul
      if (I < J) {
        float2 v = RP[J][I];
        RP[I][J] = make_float2(v.x, -v.y);
      }
    }
    __syncthreads();

    // ---- unnormalized Gauss-Jordan on [R | P]: ONE barrier per step.
    // Step j: rows i!=j:  RP[i][k] -= (RP[i][j]/RP[j][j]) * RP[j][k], k>j.
    // Row j and column j are never written during step j -> no intra-step hazard.
    for (int j = 0; j < KC; ++j) {
      if (tid < 480 && srow != j) {
        float2 pv = RP[j][j];
        float idn = 1.0f / (pv.x*pv.x + pv.y*pv.y);
        float2 lij = RP[srow][j];
        float2 fij = make_float2((lij.x*pv.x + lij.y*pv.y) * idn,
                                 (lij.y*pv.x - lij.x*pv.y) * idn);
        for (int k = j + 1 + scol; k < NC; k += 12) {
          float2 c = RP[j][k];
          float sx = fij.x*c.x - fij.y*c.y;
          float sy = fij.x*c.y + fij.y*c.x;
          RP[srow][k].x -= sx;
          RP[srow][k].y -= sy;
        }
      }
      __syncthreads();
    }
    // R is now diagonal; X = R^-1 P obtained by scaling P-columns by 1/diag
    if (tid < KC * Cc) {               // 320 entries
      int i = tid >> 3, ee = tid & 7;
      float2 pv = RP[i][i];
      float idn = 1.0f / (pv.x*pv.x + pv.y*pv.y);
      float2 p2 = RP[i][KC + ee];
      RP[i][KC + ee] = make_float2((p2.x*pv.x + p2.y*pv.y) * idn,
                                   (p2.y*pv.x - p2.x*pv.y) * idn);
    }
    __syncthreads();
  }
}

// (B,F,C,T) float2 -> masked (B,T,C,F) re/im planes
__global__ __launch_bounds__(256) void k_tout(const float2* __restrict__ enh,
                                              const int* __restrict__ ilens,
                                              float* __restrict__ out_re,
                                              float* __restrict__ out_im) {
  __shared__ float2 tile[32][33];
  int t0 = blockIdx.x * 32, f0 = blockIdx.y * 32;
  int b = blockIdx.z >> 3, c = blockIdx.z & 7;
  int tx = threadIdx.x & 31, ty = threadIdx.x >> 5;
#pragma unroll
  for (int ii = 0; ii < 4; ++ii) {
    int f = f0 + ty + 8 * ii, t = t0 + tx;
    if (f < Ff && t < Tt)
      tile[ty + 8 * ii][tx] = enh[(((size_t)b * Ff + f) * Cc + c) * Tt + t];
  }
  __syncthreads();
  int il = ilens[b];
#pragma unroll
  for (int ii = 0; ii < 4; ++ii) {
    int t = t0 + ty + 8 * ii, f = f0 + tx;
    if (t < Tt && f < Ff) {
      float2 v = tile[tx][ty + 8 * ii];
      if (t >= il) v = make_float2(0.f, 0.f);
      size_t idx = (((size_t)b * Tt + t) * Cc + c) * Ff + f;
      out_re[idx] = v.x;
      out_im[idx] = v.y;
    }
  }
}

extern "C" void kernel_launch(void* const* d_in, const int* in_sizes, int n_in,
                              void* d_out, int out_size, void* d_ws, size_t ws_size,
                              hipStream_t stream) {
  const float* in_re = (const float*)d_in[0];
  const float* in_im = (const float*)d_in[1];
  const int* ilens = (const int*)d_in[2];
  float* out_re = (float*)d_out;
  float* out_im = out_re + NTOT;

  size_t ybytes = (size_t)Bb * Ff * Cc * Tt * sizeof(float2);  // 78,950,400 B
  int have_yt = ws_size >= ybytes;
  // enh ALIASES Yt: k_wpe block bf stages Yt[bf] into LDS before writing enh[bf],
  // and no block touches another block's slice -> race-free, halves ws need.
  float2* Yt  = (float2*)d_ws;
  float2* enh = (float2*)d_ws;

  if (have_yt) {
    dim3 g((Ff + 31) / 32, (Tt + 31) / 32, Bb * Cc);
    k_tin<<<g, dim3(256), 0, stream>>>(in_re, in_im, Yt);
  }
  {
    dim3 g(Bb * Ff);
    k_wpe<<<g, dim3(512), 0, stream>>>(Yt, enh, in_re, in_im, ilens,
                                       out_re, out_im,
                                       have_yt ? 0 : 1, have_yt ? 0 : 1);
  }
  if (have_yt) {
    dim3 g((Tt + 31) / 32, (Ff + 31) / 32, Bb * Cc);
    k_tout<<<g, dim3(256), 0, stream>>>(enh, ilens, out_re, out_im);
  }
}

// Round 9
// 812.907 us; speedup vs baseline: 1.4017x; 1.0040x over previous
//
#include <hip/hip_runtime.h>
#include <hip/hip_bf16.h>

#define Bb 8
#define Tt 600
#define Cc 8
#define Ff 257
#define TAPS 5
#define DELAY 3
#define KC 40            // TAPS*C
#define NC 48            // KC + C (R columns | P columns)
#define RPW 53           // RP row stride (float2): 106 dw, gcd(106,32)=2 -> 16-bank row spread
#define TQ 593           // T - DELAY - TAPS + 1
#define TP 606           // Yl row stride (float2): d*28%32 all-distinct, conflict-free
#define WLN 608          // wl with zero pads [600..607]
#define AEND 597         // TQ + 4: lag-product a-range
#define EPSF 1e-10f
#define NTOT (Bb*Tt*Cc*Ff)   // 9,868,800

// Lower-triangle tap-block tables: id -> (k,l), grouped by lag tau=k-l.
constexpr int kABASE[5] = {0, 5, 9, 12, 14};
constexpr int kK15[15] = {0,1,2,3,4, 1,2,3,4, 2,3,4, 3,4, 4};
constexpr int kL15[15] = {0,1,2,3,4, 0,1,2,3, 0,1,2, 0,1, 0};

// (B,T,C,F) re/im planes -> (B,F,C,T) interleaved float2
__global__ __launch_bounds__(256) void k_tin(const float* __restrict__ in_re,
                                             const float* __restrict__ in_im,
                                             float2* __restrict__ Yt) {
  __shared__ float2 tile[32][33];
  int f0 = blockIdx.x * 32, t0 = blockIdx.y * 32;
  int b = blockIdx.z >> 3, c = blockIdx.z & 7;
  int tx = threadIdx.x & 31, ty = threadIdx.x >> 5;
#pragma unroll
  for (int ii = 0; ii < 4; ++ii) {
    int t = t0 + ty + 8 * ii, f = f0 + tx;
    if (t < Tt && f < Ff) {
      size_t idx = (((size_t)b * Tt + t) * Cc + c) * Ff + f;
      tile[ty + 8 * ii][tx] = make_float2(in_re[idx], in_im[idx]);
    }
  }
  __syncthreads();
#pragma unroll
  for (int ii = 0; ii < 4; ++ii) {
    int f = f0 + ty + 8 * ii, t = t0 + tx;
    if (f < Ff && t < Tt) {
      size_t o = (((size_t)b * Ff + f) * Cc + c) * Tt + t;
      Yt[o] = tile[tx][ty + 8 * ii];
    }
  }
}

// Lag-product accumulation, SPLIT across two lag-sets so each wave's live
// register state fits comfortably under the compiler's 64-VGPR allocation
// (round 8: one-wave-does-all needed ~80 live -> scratch spills, +340 MB HBM).
//   p_tau(a) = conj(Yd[a])*Ye[a+tau]     (shared by all blocks of lag tau)
//   R[k][k-tau] += wl[a+3+k] * p_tau(a)  (w real -> 2 FMA per block)
//   P[tau-3]    += wl[a+tau] * p_tau(a)  (tau = 3..7)
// SET 0: tau 0..2 -> 12 R-blocks (ids 0..11);  36 FMA/a, ~50 live floats
// SET 1: tau 3..7 -> 3 R-blocks (ids 12..14, local 0..2) + 5 P; 36 FMA/a, ~50
// Zero-padded wl ([0..6], [600..607]) + Yl tail zeros make range ends vanish.
template<int SET>
__device__ __forceinline__ void accum_lag(const float2* __restrict__ Yd,
                                          const float2* __restrict__ Ye,
                                          const float* __restrict__ wl,
                                          int aA, int aB,
                                          float2 (&racu)[12], float2 (&pac)[5]) {
  constexpr int TAU0 = (SET == 0) ? 0 : 3;
  constexpr int TAU1 = (SET == 0) ? 2 : 7;
  constexpr int YEM  = (SET == 0) ? 3 : 7;   // ye ring mask (span 4 / span 8)
  float2 ye[YEM + 1];
  float w8[8];
  if constexpr (SET == 0) {
#pragma unroll
    for (int j = 0; j < 3; ++j) ye[j] = Ye[aA + j];
  } else {
#pragma unroll
    for (int j = 3; j < 7; ++j) ye[j & YEM] = Ye[aA + j];
  }
#pragma unroll
  for (int j = 3; j < 7; ++j) w8[j & 7] = wl[aA + j];

  int len = aB - aA;
  int i = 0;
  for (; i + 8 <= len; i += 8) {
#pragma unroll
    for (int u = 0; u < 8; ++u) {            // full unroll: all &-indices fold
      int a_ = aA + i + u;
      float2 yd_ = Yd[a_];
      if constexpr (SET == 0) ye[(u + 3) & YEM] = Ye[a_ + 3];
      else                    ye[(u + 7) & YEM] = Ye[a_ + 7];
      w8[(u + 7) & 7] = wl[a_ + 7];
#pragma unroll
      for (int tau = TAU0; tau <= TAU1; ++tau) {
        float2 yv = ye[(u + tau) & YEM];
        float px = fmaf(yd_.y, yv.y, yd_.x * yv.x);
        float py = fmaf(yd_.x, yv.y, -(yd_.y * yv.x));
        if (tau <= 4) {
#pragma unroll
          for (int k = tau; k < 5; ++k) {
            float wk = w8[(u + 3 + k) & 7];
            int id = kABASE[tau] + (k - tau) - (SET ? 12 : 0);
            racu[id].x = fmaf(wk, px, racu[id].x);
            racu[id].y = fmaf(wk, py, racu[id].y);
          }
        }
        if constexpr (SET == 1) {
          float wk = w8[(u + tau) & 7];
          pac[tau - 3].x = fmaf(wk, px, pac[tau - 3].x);
          pac[tau - 3].y = fmaf(wk, py, pac[tau - 3].y);
        }
      }
    }
  }
  for (; i < len; ++i) {                     // tail <=7: direct LDS reads
    int a = aA + i;
    float2 yd = Yd[a];
#pragma unroll
    for (int tau = TAU0; tau <= TAU1; ++tau) {
      float2 yv = Ye[a + tau];
      float px = fmaf(yd.y, yv.y, yd.x * yv.x);
      float py = fmaf(yd.x, yv.y, -(yd.y * yv.x));
      if (tau <= 4) {
#pragma unroll
        for (int k = tau; k < 5; ++k) {
          float wk = wl[a + 3 + k];
          int id = kABASE[tau] + (k - tau) - (SET ? 12 : 0);
          racu[id].x = fmaf(wk, px, racu[id].x);
          racu[id].y = fmaf(wk, py, racu[id].y);
        }
      }
      if constexpr (SET == 1) {
        float wk = wl[a + tau];
        pac[tau - 3].x = fmaf(wk, px, pac[tau - 3].x);
        pac[tau - 3].y = fmaf(wk, py, pac[tau - 3].y);
      }
    }
  }
}

// One block (512 thr) per (b,f): full 2-iteration WPE.
// Accumulation: 8 waves = 4 a-groups x 2 lag-sets (36 FMA/a each, balanced);
// 4-pass merge (sets write disjoint RP regions); conj-reconstruct; 1-barrier
// GJ solve.  enh aliases Yt.
__global__ void __launch_bounds__(512, 4)
__attribute__((amdgpu_waves_per_eu(4, 4)))
k_wpe(const float2* __restrict__ Yt,
      float2* __restrict__ enh,
      const float* __restrict__ in_re,
      const float* __restrict__ in_im,
      const int* __restrict__ ilens,
      float* __restrict__ out_re,
      float* __restrict__ out_im,
      int load_direct, int store_direct) {
  __shared__ float2 Yl[Cc][TP];        // 8 x 606 complex = 38784 B
  __shared__ float2 RP[KC][RPW];       // [R | P] 40 x 53  = 16960 B
  __shared__ float wl[WLN];            // 2432 B  -> total 58176 B

  // XCD-chunked bijective swizzle (2056 % 8 == 0): bf = (orig%8)*257 + orig/8
  int orig = blockIdx.x;
  int bf = (orig & 7) * (Bb * Ff / 8) + (orig >> 3);
  int b = bf / Ff, f = bf % Ff;
  int tid = threadIdx.x;               // 0..511
  int group = tid >> 6;                // wave id
  int lane = tid & 63;
  int d = lane & 7;                    // row channel
  int e = lane >> 3;                   // col channel
  int tg = group >> 1;                 // a-group 0..3
  int ls = group & 1;                  // lag-set: 0 -> tau 0..2, 1 -> tau 3..7

  // solve mapping: thread = (row, col-chunk), 480 active
  int srow = tid % KC;                 // const divisor -> magic mul, hoisted
  int scol = tid / KC;                 // 0..12

  // ---- stage Y into LDS (+ zero pads enabling the maskless lag loop)
  if (tid < 8) wl[600 + tid] = 0.f;
  if (tid < 48) { int c = tid / 6; Yl[c][600 + tid % 6] = make_float2(0.f, 0.f); }
  if (!load_direct) {
    const float4* Yg = (const float4*)(Yt + (size_t)bf * (Cc * Tt));
    for (int i = tid; i < Cc * Tt / 2; i += 512) {
      float4 v = Yg[i];
      int c = i / (Tt / 2), t2 = (i % (Tt / 2)) * 2;
      *(float4*)&Yl[c][t2] = v;        // 16B aligned: 606*c + t2 even
    }
  } else {
    for (int i = tid; i < Cc * Tt; i += 512) {
      int c = i / Tt, t = i % Tt;
      size_t idx = (((size_t)b * Tt + t) * Cc + c) * Ff + f;
      Yl[c][t] = make_float2(in_re[idx], in_im[idx]);
    }
  }
  __syncthreads();

  const float2* Yd = &Yl[d][0];
  const float2* Ye = &Yl[e][0];

  int aA = (AEND * tg) >> 2;
  int aB = (AEND * (tg + 1)) >> 2;

  for (int iter = 0; iter < 3; ++iter) {
    // ---- weights (iter 0 from Y); iter 1: apply filter -> weights; iter 2: apply -> store
    // wl[t<7] forced to 0: unused by the weights' consumers, required as the
    // zero pad of the lag-product loop.
    if (iter == 0) {
      for (int t = tid; t < Tt; t += 512) {
        float s = 0.f;
#pragma unroll
        for (int c = 0; c < Cc; ++c) { float2 y = Yl[c][t]; s += y.x*y.x + y.y*y.y; }
        wl[t] = (t < 7) ? 0.f : 1.0f / fmaxf(s * 0.125f, EPSF);
      }
    } else {
      int il = (iter == 2 && store_direct) ? ilens[b] : Tt;
      for (int t = tid; t < Tt; t += 512) {
        float2 acc[Cc];
#pragma unroll
        for (int ee = 0; ee < Cc; ++ee) acc[ee] = Yl[ee][t];
        for (int p = 0; p < TAPS; ++p) {
          int ts = t - DELAY - p;
          if (ts < 0) break;   // zero-padded region
#pragma unroll
          for (int dd = 0; dd < Cc; ++dd) {
            float2 u = Yl[dd][ts];
#pragma unroll
            for (int ee = 0; ee < Cc; ++ee) {
              float2 g = RP[p * Cc + dd][KC + ee];  // uniform addr across wave -> broadcast
              acc[ee].x -= g.x*u.x - g.y*u.y;
              acc[ee].y -= g.x*u.y + g.y*u.x;
            }
          }
        }
        if (iter == 1) {
          float s = 0.f;
#pragma unroll
          for (int ee = 0; ee < Cc; ++ee) s += acc[ee].x*acc[ee].x + acc[ee].y*acc[ee].y;
          wl[t] = (t < 7) ? 0.f : 1.0f / fmaxf(s * 0.125f, EPSF);
        } else {
          if (!store_direct) {
            float2* Eg = enh + (size_t)bf * (Cc * Tt);
#pragma unroll
            for (int ee = 0; ee < Cc; ++ee) Eg[ee * Tt + t] = acc[ee];  // own Yt slice
          } else {
            bool live = (t < il);
#pragma unroll
            for (int ee = 0; ee < Cc; ++ee) {
              float2 v = live ? acc[ee] : make_float2(0.f, 0.f);
              size_t idx = (((size_t)b * Tt + t) * Cc + ee) * Ff + f;
              out_re[idx] = v.x;
              out_im[idx] = v.y;
            }
          }
        }
      }
    }
    if (iter == 2) break;
    __syncthreads();   // (A) wl ready; apply-phase G reads done

    // ---- accumulate: lag-split register subtiles (zero-init per path only,
    // so each wave's dead half stays dead for the allocator)
    float2 racu[12], pac[5];
    if (ls == 0) {
#pragma unroll
      for (int j = 0; j < 12; ++j) racu[j] = make_float2(0.f, 0.f);
      accum_lag<0>(Yd, Ye, wl, aA, aB, racu, pac);
    } else {
#pragma unroll
      for (int j = 0; j < 3; ++j) racu[j] = make_float2(0.f, 0.f);
#pragma unroll
      for (int j = 0; j < 5; ++j) pac[j] = make_float2(0.f, 0.f);
      accum_lag<1>(Yd, Ye, wl, aA, aB, racu, pac);
    }

    // ---- merge the 4 a-group partials; the two lag-sets write DISJOINT RP
    // regions (ids 0..11 vs ids 12..14 + P cols) so they go concurrently.
    // Pass 0 writes (EPS folded onto the diagonal); no FP atomics.
    for (int gp = 0; gp < 4; ++gp) {
      if (tg == gp) {
        if (ls == 0) {
          if (gp == 0) {
#pragma unroll
            for (int id = 0; id < 12; ++id) {
              float2 v = racu[id];
              if (id < 5 && d == e) v.x += EPSF;   // ids 0..4 are diag blocks
              RP[kK15[id]*8 + d][kL15[id]*8 + e] = v;
            }
          } else {
#pragma unroll
            for (int id = 0; id < 12; ++id) {
              float2 v = RP[kK15[id]*8 + d][kL15[id]*8 + e];
              v.x += racu[id].x; v.y += racu[id].y;
              RP[kK15[id]*8 + d][kL15[id]*8 + e] = v;
            }
          }
        } else {
          if (gp == 0) {
#pragma unroll
            for (int j = 0; j < 3; ++j)
              RP[kK15[12+j]*8 + d][kL15[12+j]*8 + e] = racu[j];
#pragma unroll
            for (int k = 0; k < 5; ++k) RP[k*8 + d][KC + e] = pac[k];
          } else {
#pragma unroll
            for (int j = 0; j < 3; ++j) {
              float2 v = RP[kK15[12+j]*8 + d][kL15[12+j]*8 + e];
              v.x += racu[j].x; v.y += racu[j].y;
              RP[kK15[12+j]*8 + d][kL15[12+j]*8 + e] = v;
            }
#pragma unroll
            for (int k = 0; k < 5; ++k) {
              float2 v = RP[k*8 + d][KC + e];
              v.x += pac[k].x; v.y += pac[k].y;
              RP[k*8 + d][KC + e] = v;
            }
          }
        }
      }
      __syncthreads();
    }

    // ---- reconstruct the upper triangle: R[I][J] = conj(R[J][I]) for I<J
    for (int idx = tid; idx < KC * KC; idx += 512) {
      int I = idx / KC, J = idx - I * KC;    // const divisor -> magic mul
      if (I < J) {
        float2 v = RP[J][I];
        RP[I][J] = make_float2(v.x, -v.y);
      }
    }
    __syncthreads();

    // ---- unnormalized Gauss-Jordan on [R | P]: ONE barrier per step.
    // Step j: rows i!=j:  RP[i][k] -= (RP[i][j]/RP[j][j]) * RP[j][k], k>j.
    // Row j and column j are never written during step j -> no intra-step hazard.
    for (int j = 0; j < KC; ++j) {
      if (tid < 480 && srow != j) {
        float2 pv = RP[j][j];
        float idn = 1.0f / (pv.x*pv.x + pv.y*pv.y);
        float2 lij = RP[srow][j];
        float2 fij = make_float2((lij.x*pv.x + lij.y*pv.y) * idn,
                                 (lij.y*pv.x - lij.x*pv.y) * idn);
        for (int k = j + 1 + scol; k < NC; k += 12) {
          float2 c = RP[j][k];
          float sx = fij.x*c.x - fij.y*c.y;
          float sy = fij.x*c.y + fij.y*c.x;
          RP[srow][k].x -= sx;
          RP[srow][k].y -= sy;
        }
      }
      __syncthreads();
    }
    // R is now diagonal; X = R^-1 P obtained by scaling P-columns by 1/diag
    if (tid < KC * Cc) {               // 320 entries
      int i = tid >> 3, ee = tid & 7;
      float2 pv = RP[i][i];
      float idn = 1.0f / (pv.x*pv.x + pv.y*pv.y);
      float2 p2 = RP[i][KC + ee];
      RP[i][KC + ee] = make_float2((p2.x*pv.x + p2.y*pv.y) * idn,
                                   (p2.y*pv.x - p2.x*pv.y) * idn);
    }
    __syncthreads();
  }
}

// (B,F,C,T) float2 -> masked (B,T,C,F) re/im planes
__global__ __launch_bounds__(256) void k_tout(const float2* __restrict__ enh,
                                              const int* __restrict__ ilens,
                                              float* __restrict__ out_re,
                                              float* __restrict__ out_im) {
  __shared__ float2 tile[32][33];
  int t0 = blockIdx.x * 32, f0 = blockIdx.y * 32;
  int b = blockIdx.z >> 3, c = blockIdx.z & 7;
  int tx = threadIdx.x & 31, ty = threadIdx.x >> 5;
#pragma unroll
  for (int ii = 0; ii < 4; ++ii) {
    int f = f0 + ty + 8 * ii, t = t0 + tx;
    if (f < Ff && t < Tt)
      tile[ty + 8 * ii][tx] = enh[(((size_t)b * Ff + f) * Cc + c) * Tt + t];
  }
  __syncthreads();
  int il = ilens[b];
#pragma unroll
  for (int ii = 0; ii < 4; ++ii) {
    int t = t0 + ty + 8 * ii, f = f0 + tx;
    if (t < Tt && f < Ff) {
      float2 v = tile[tx][ty + 8 * ii];
      if (t >= il) v = make_float2(0.f, 0.f);
      size_t idx = (((size_t)b * Tt + t) * Cc + c) * Ff + f;
      out_re[idx] = v.x;
      out_im[idx] = v.y;
    }
  }
}

extern "C" void kernel_launch(void* const* d_in, const int* in_sizes, int n_in,
                              void* d_out, int out_size, void* d_ws, size_t ws_size,
                              hipStream_t stream) {
  const float* in_re = (const float*)d_in[0];
  const float* in_im = (const float*)d_in[1];
  const int* ilens = (const int*)d_in[2];
  float* out_re = (float*)d_out;
  float* out_im = out_re + NTOT;

  size_t ybytes = (size_t)Bb * Ff * Cc * Tt * sizeof(float2);  // 78,950,400 B
  int have_yt = ws_size >= ybytes;
  // enh ALIASES Yt: k_wpe block bf stages Yt[bf] into LDS before writing enh[bf],
  // and no block touches another block's slice -> race-free, halves ws need.
  float2* Yt  = (float2*)d_ws;
  float2* enh = (float2*)d_ws;

  if (have_yt) {
    dim3 g((Ff + 31) / 32, (Tt + 31) / 32, Bb * Cc);
    k_tin<<<g, dim3(256), 0, stream>>>(in_re, in_im, Yt);
  }
  {
    dim3 g(Bb * Ff);
    k_wpe<<<g, dim3(512), 0, stream>>>(Yt, enh, in_re, in_im, ilens,
                                       out_re, out_im,
                                       have_yt ? 0 : 1, have_yt ? 0 : 1);
  }
  if (have_yt) {
    dim3 g((Tt + 31) / 32, (Ff + 31) / 32, Bb * Cc);
    k_tout<<<g, dim3(256), 0, stream>>>(enh, ilens, out_re, out_im);
  }
}

// Round 10
// 711.562 us; speedup vs baseline: 1.6014x; 1.1424x over previous
//
#include <hip/hip_runtime.h>
#include <hip/hip_bf16.h>

#define Bb 8
#define Tt 600
#define Cc 8
#define Ff 257
#define TAPS 5
#define DELAY 3
#define KC 40            // TAPS*C
#define NC 48            // KC + C (R columns | P columns)
#define RPW 51           // RP row stride (float2): 102 dw, gcd(102%32=6,32)=2 -> 16-bank spread
#define TQ 593           // T - DELAY - TAPS + 1
#define TP 606           // Yl row stride (float2): d*28%32 all-distinct, conflict-free; even for float4 staging
#define WLN 604          // wl2 with zero pads [600..603] (max read index 603)
#define AEND 597         // TQ + 4: lag-product a-range
#define EPSF 1e-10f
#define NTOT (Bb*Tt*Cc*Ff)   // 9,868,800

// Native 2-float vector so the backend can emit v_pk_fma_f32 (VOP3P packed
// FP32, gfx90a+; this is the only path to gfx950's 157 TF FP32 rate).
typedef float v2f __attribute__((ext_vector_type(2)));

#if __has_builtin(__builtin_elementwise_fma)
#define PKFMA(a, b, c) __builtin_elementwise_fma((a), (b), (c))
#else
__device__ __forceinline__ v2f pkfma_(v2f a, v2f b, v2f c) {
  v2f r; r.x = fmaf(a.x, b.x, c.x); r.y = fmaf(a.y, b.y, c.y); return r;
}
#define PKFMA(a, b, c) pkfma_((a), (b), (c))
#endif

// p = conj(yd)*yv = (yd.x*yv.x + yd.y*yv.y, yd.x*yv.y - yd.y*yv.x)
// packed: t = yd.xx * yv;  p = (yd.y, -yd.y) (*) yv.yx + t
__device__ __forceinline__ v2f conjmul(v2f yd, v2f yv) {
  v2f t = yd.xx * yv;
  v2f n; n.x = yd.y; n.y = -yd.y;
  return PKFMA(n, yv.yx, t);
}

// Lower-triangle tap-block tables: id -> (k,l), grouped by lag tau=k-l.
constexpr int kABASE[5] = {0, 5, 9, 12, 14};
constexpr int kK15[15] = {0,1,2,3,4, 1,2,3,4, 2,3,4, 3,4, 4};
constexpr int kL15[15] = {0,1,2,3,4, 0,1,2,3, 0,1,2, 0,1, 0};

// (B,T,C,F) re/im planes -> (B,F,C,T) interleaved float2
__global__ __launch_bounds__(256) void k_tin(const float* __restrict__ in_re,
                                             const float* __restrict__ in_im,
                                             float2* __restrict__ Yt) {
  __shared__ float2 tile[32][33];
  int f0 = blockIdx.x * 32, t0 = blockIdx.y * 32;
  int b = blockIdx.z >> 3, c = blockIdx.z & 7;
  int tx = threadIdx.x & 31, ty = threadIdx.x >> 5;
#pragma unroll
  for (int ii = 0; ii < 4; ++ii) {
    int t = t0 + ty + 8 * ii, f = f0 + tx;
    if (t < Tt && f < Ff) {
      size_t idx = (((size_t)b * Tt + t) * Cc + c) * Ff + f;
      tile[ty + 8 * ii][tx] = make_float2(in_re[idx], in_im[idx]);
    }
  }
  __syncthreads();
#pragma unroll
  for (int ii = 0; ii < 4; ++ii) {
    int f = f0 + ty + 8 * ii, t = t0 + tx;
    if (f < Ff && t < Tt) {
      size_t o = (((size_t)b * Ff + f) * Cc + c) * Tt + t;
      Yt[o] = tile[tx][ty + 8 * ii];
    }
  }
}

// Lag-product accumulation (packed).  Two lag-sets across wave pairs:
//   SET 0: tau 0..2 -> 12 R-blocks;  SET 1: tau 3..7 -> 3 R-blocks + 5 P.
//   p_tau(a) = conj(Yd[a])*Ye[a+tau];  R/P updates are w*(px,py) pairs with
//   REAL w -> one v_pk_fma_f32 each.  w comes pre-duplicated from LDS wl2
//   ((w,w) per t, ds_read_b64 broadcast: no splat moves).
// Zero-padded wl2 ([0..6], [600..603]) + Yl tail zeros make range ends vanish.
template<int SET>
__device__ __forceinline__ void accum_lag(const v2f* __restrict__ Yd,
                                          const v2f* __restrict__ Ye,
                                          const v2f* __restrict__ wl2,
                                          int aA, int aB,
                                          v2f (&racu)[12], v2f (&pac)[5]) {
  constexpr int YEM = (SET == 0) ? 3 : 7;   // ye ring mask (span 4 / span 8)
  v2f ye[YEM + 1];
  if constexpr (SET == 0) {
#pragma unroll
    for (int j = 0; j < 3; ++j) ye[j] = Ye[aA + j];
  } else {
#pragma unroll
    for (int j = 3; j < 7; ++j) ye[j & YEM] = Ye[aA + j];
  }

  int len = aB - aA;
  int i = 0;
  for (; i + 8 <= len; i += 8) {
#pragma unroll
    for (int u = 0; u < 8; ++u) {            // full unroll: all &-indices fold
      int a_ = aA + i + u;
      v2f yd_ = Yd[a_];
      v2f w_[5];
#pragma unroll
      for (int j = 0; j < 5; ++j) w_[j] = wl2[a_ + 3 + j];  // wave-uniform bcast
      if constexpr (SET == 0) {
        ye[(u + 3) & YEM] = Ye[a_ + 3];
#pragma unroll
        for (int tau = 0; tau <= 2; ++tau) {
          v2f yv = ye[(u + tau) & YEM];
          v2f p = conjmul(yd_, yv);
#pragma unroll
          for (int k = tau; k < 5; ++k) {
            int id = kABASE[tau] + (k - tau);
            racu[id] = PKFMA(w_[k], p, racu[id]);
          }
        }
      } else {
        ye[(u + 7) & YEM] = Ye[a_ + 7];
#pragma unroll
        for (int tau = 3; tau <= 7; ++tau) {
          v2f yv = ye[(u + tau) & YEM];
          v2f p = conjmul(yd_, yv);
          if (tau == 3) {
            racu[0] = PKFMA(w_[3], p, racu[0]);   // id 12: (3,0)
            racu[1] = PKFMA(w_[4], p, racu[1]);   // id 13: (4,1)
          }
          if (tau == 4) racu[2] = PKFMA(w_[4], p, racu[2]);  // id 14: (4,0)
          pac[tau - 3] = PKFMA(w_[tau - 3], p, pac[tau - 3]);
        }
      }
    }
  }
  for (; i < len; ++i) {                     // tail <=7: direct LDS reads
    int a = aA + i;
    v2f yd = Yd[a];
    if constexpr (SET == 0) {
#pragma unroll
      for (int tau = 0; tau <= 2; ++tau) {
        v2f p = conjmul(yd, Ye[a + tau]);
#pragma unroll
        for (int k = tau; k < 5; ++k) {
          int id = kABASE[tau] + (k - tau);
          racu[id] = PKFMA(wl2[a + 3 + k], p, racu[id]);
        }
      }
    } else {
#pragma unroll
      for (int tau = 3; tau <= 7; ++tau) {
        v2f p = conjmul(yd, Ye[a + tau]);
        if (tau == 3) {
          racu[0] = PKFMA(wl2[a + 6], p, racu[0]);
          racu[1] = PKFMA(wl2[a + 7], p, racu[1]);
        }
        if (tau == 4) racu[2] = PKFMA(wl2[a + 7], p, racu[2]);
        pac[tau - 3] = PKFMA(wl2[a + tau], p, pac[tau - 3]);
      }
    }
  }
}

// One block (512 thr) per (b,f): full 2-iteration WPE.
// Accumulation: 8 waves = 4 a-groups x 2 lag-sets, packed FP32 throughout;
// 4-pass merge; conj-reconstruct; 1-barrier GJ solve; packed apply via the
// sign-prepared Gp table ((-gx,-gx,gy,-gy) per filter coeff: complex MAC =
// 2 pk_fma).  enh aliases Yt.
__global__ void __launch_bounds__(512, 4)
__attribute__((amdgpu_waves_per_eu(4, 4)))
k_wpe(const float2* __restrict__ Yt,
      float2* __restrict__ enh,
      const float* __restrict__ in_re,
      const float* __restrict__ in_im,
      const int* __restrict__ ilens,
      float* __restrict__ out_re,
      float* __restrict__ out_im,
      int load_direct, int store_direct) {
  __shared__ float2 Yl[Cc][TP];        // 8 x 606 complex = 38784 B
  __shared__ float2 RP[KC][RPW];       // [R | P] 40 x 51  = 16320 B
  __shared__ float2 wl2s[WLN];         // (w,w) pairs       =  4832 B
  __shared__ float4 Gp[KC][Cc];        // packed filter     =  5120 B -> 65056 B

  // XCD-chunked bijective swizzle (2056 % 8 == 0): bf = (orig%8)*257 + orig/8
  int orig = blockIdx.x;
  int bf = (orig & 7) * (Bb * Ff / 8) + (orig >> 3);
  int b = bf / Ff, f = bf % Ff;
  int tid = threadIdx.x;               // 0..511
  int group = tid >> 6;                // wave id
  int lane = tid & 63;
  int d = lane & 7;                    // row channel
  int e = lane >> 3;                   // col channel
  int tg = group >> 1;                 // a-group 0..3
  int ls = group & 1;                  // lag-set: 0 -> tau 0..2, 1 -> tau 3..7

  // solve mapping: thread = (row, col-chunk), 480 active
  int srow = tid % KC;                 // const divisor -> magic mul, hoisted
  int scol = tid / KC;                 // 0..12

  // ---- stage Y into LDS (+ zero pads enabling the maskless lag loop)
  if (tid < 4) wl2s[600 + tid] = make_float2(0.f, 0.f);
  if (tid < 48) { int c = tid / 6; Yl[c][600 + tid % 6] = make_float2(0.f, 0.f); }
  if (!load_direct) {
    const float4* Yg = (const float4*)(Yt + (size_t)bf * (Cc * Tt));
    for (int i = tid; i < Cc * Tt / 2; i += 512) {
      float4 v = Yg[i];
      int c = i / (Tt / 2), t2 = (i % (Tt / 2)) * 2;
      *(float4*)&Yl[c][t2] = v;        // 16B aligned: 606*c + t2 even
    }
  } else {
    for (int i = tid; i < Cc * Tt; i += 512) {
      int c = i / Tt, t = i % Tt;
      size_t idx = (((size_t)b * Tt + t) * Cc + c) * Ff + f;
      Yl[c][t] = make_float2(in_re[idx], in_im[idx]);
    }
  }
  __syncthreads();

  const v2f* Yd = (const v2f*)&Yl[d][0];
  const v2f* Ye = (const v2f*)&Yl[e][0];
  const v2f* wl2 = (const v2f*)&wl2s[0];

  int aA = (AEND * tg) >> 2;
  int aB = (AEND * (tg + 1)) >> 2;

  for (int iter = 0; iter < 3; ++iter) {
    // ---- weights (iter 0 from Y); iter 1: apply filter -> weights; iter 2: apply -> store
    // wl2[t<7] forced to 0: unused by consumers, required as the lag-loop pad.
    if (iter == 0) {
      for (int t = tid; t < Tt; t += 512) {
        float s = 0.f;
#pragma unroll
        for (int c = 0; c < Cc; ++c) { float2 y = Yl[c][t]; s += y.x*y.x + y.y*y.y; }
        float w = (t < 7) ? 0.f : 1.0f / fmaxf(s * 0.125f, EPSF);
        wl2s[t] = make_float2(w, w);
      }
    } else {
      int il = (iter == 2 && store_direct) ? ilens[b] : Tt;
      for (int t = tid; t < Tt; t += 512) {
        v2f acc[Cc];
#pragma unroll
        for (int ee = 0; ee < Cc; ++ee) acc[ee] = *(const v2f*)&Yl[ee][t];
        for (int p = 0; p < TAPS; ++p) {
          int ts = t - DELAY - p;
          if (ts < 0) break;   // zero-padded region
#pragma unroll
          for (int dd = 0; dd < Cc; ++dd) {
            v2f u2 = *(const v2f*)&Yl[dd][ts];
            v2f us = u2.yx;
            const float4* gq = &Gp[p * Cc + dd][0];   // uniform addr -> bcast
#pragma unroll
            for (int ee = 0; ee < Cc; ++ee) {
              float4 g4 = gq[ee];
              v2f gA; gA.x = g4.x; gA.y = g4.y;
              v2f gB; gB.x = g4.z; gB.y = g4.w;
              acc[ee] = PKFMA(gA, u2, acc[ee]);
              acc[ee] = PKFMA(gB, us, acc[ee]);
            }
          }
        }
        if (iter == 1) {
          float s = 0.f;
#pragma unroll
          for (int ee = 0; ee < Cc; ++ee) s += acc[ee].x*acc[ee].x + acc[ee].y*acc[ee].y;
          float w = (t < 7) ? 0.f : 1.0f / fmaxf(s * 0.125f, EPSF);
          wl2s[t] = make_float2(w, w);
        } else {
          if (!store_direct) {
            float2* Eg = enh + (size_t)bf * (Cc * Tt);
#pragma unroll
            for (int ee = 0; ee < Cc; ++ee)
              Eg[ee * Tt + t] = make_float2(acc[ee].x, acc[ee].y);  // own Yt slice
          } else {
            bool live = (t < il);
#pragma unroll
            for (int ee = 0; ee < Cc; ++ee) {
              float vx = live ? acc[ee].x : 0.f, vy = live ? acc[ee].y : 0.f;
              size_t idx = (((size_t)b * Tt + t) * Cc + ee) * Ff + f;
              out_re[idx] = vx;
              out_im[idx] = vy;
            }
          }
        }
      }
    }
    if (iter == 2) break;
    __syncthreads();   // (A) wl2 ready; apply-phase Gp reads done

    // ---- accumulate: lag-split packed register subtiles
    v2f racu[12], pac[5];
    if (ls == 0) {
#pragma unroll
      for (int j = 0; j < 12; ++j) racu[j] = (v2f)(0.f);
      accum_lag<0>(Yd, Ye, wl2, aA, aB, racu, pac);
    } else {
#pragma unroll
      for (int j = 0; j < 3; ++j) racu[j] = (v2f)(0.f);
#pragma unroll
      for (int j = 0; j < 5; ++j) pac[j] = (v2f)(0.f);
      accum_lag<1>(Yd, Ye, wl2, aA, aB, racu, pac);
    }

    // ---- merge the 4 a-group partials; the two lag-sets write DISJOINT RP
    // regions (ids 0..11 vs ids 12..14 + P cols) so they go concurrently.
    // Pass 0 writes (EPS folded onto the diagonal); no FP atomics.
    for (int gp = 0; gp < 4; ++gp) {
      if (tg == gp) {
        if (ls == 0) {
          if (gp == 0) {
#pragma unroll
            for (int id = 0; id < 12; ++id) {
              float2 v = make_float2(racu[id].x, racu[id].y);
              if (id < 5 && d == e) v.x += EPSF;   // ids 0..4 are diag blocks
              RP[kK15[id]*8 + d][kL15[id]*8 + e] = v;
            }
          } else {
#pragma unroll
            for (int id = 0; id < 12; ++id) {
              float2 v = RP[kK15[id]*8 + d][kL15[id]*8 + e];
              v.x += racu[id].x; v.y += racu[id].y;
              RP[kK15[id]*8 + d][kL15[id]*8 + e] = v;
            }
          }
        } else {
          if (gp == 0) {
#pragma unroll
            for (int j = 0; j < 3; ++j)
              RP[kK15[12+j]*8 + d][kL15[12+j]*8 + e] =
                  make_float2(racu[j].x, racu[j].y);
#pragma unroll
            for (int k = 0; k < 5; ++k)
              RP[k*8 + d][KC + e] = make_float2(pac[k].x, pac[k].y);
          } else {
#pragma unroll
            for (int j = 0; j < 3; ++j) {
              float2 v = RP[kK15[12+j]*8 + d][kL15[12+j]*8 + e];
              v.x += racu[j].x; v.y += racu[j].y;
              RP[kK15[12+j]*8 + d][kL15[12+j]*8 + e] = v;
            }
#pragma unroll
            for (int k = 0; k < 5; ++k) {
              float2 v = RP[k*8 + d][KC + e];
              v.x += pac[k].x; v.y += pac[k].y;
              RP[k*8 + d][KC + e] = v;
            }
          }
        }
      }
      __syncthreads();
    }

    // ---- reconstruct the upper triangle: R[I][J] = conj(R[J][I]) for I<J
    for (int idx = tid; idx < KC * KC; idx += 512) {
      int I = idx / KC, J = idx - I * KC;    // const divisor -> magic mul
      if (I < J) {
        float2 v = RP[J][I];
        RP[I][J] = make_float2(v.x, -v.y);
      }
    }
    __syncthreads();

    // ---- unnormalized Gauss-Jordan on [R | P]: ONE barrier per step.
    // Step j: rows i!=j:  RP[i][k] -= (RP[i][j]/RP[j][j]) * RP[j][k], k>j.
    // Row j and column j are never written during step j -> no intra-step hazard.
    for (int j = 0; j < KC; ++j) {
      if (tid < 480 && srow != j) {
        float2 pv = RP[j][j];
        float idn = 1.0f / (pv.x*pv.x + pv.y*pv.y);
        float2 lij = RP[srow][j];
        float2 fij = make_float2((lij.x*pv.x + lij.y*pv.y) * idn,
                                 (lij.y*pv.x - lij.x*pv.y) * idn);
        for (int k = j + 1 + scol; k < NC; k += 12) {
          float2 c = RP[j][k];
          float sx = fij.x*c.x - fij.y*c.y;
          float sy = fij.x*c.y + fij.y*c.x;
          RP[srow][k].x -= sx;
          RP[srow][k].y -= sy;
        }
      }
      __syncthreads();
    }
    // R is now diagonal; X = R^-1 P.  Write the packed, sign-prepared filter
    // table the apply phase consumes: Gp = (-X.x, -X.x, X.y, -X.y).
    if (tid < KC * Cc) {               // 320 entries
      int i = tid >> 3, ee = tid & 7;
      float2 pv = RP[i][i];
      float idn = 1.0f / (pv.x*pv.x + pv.y*pv.y);
      float2 p2 = RP[i][KC + ee];
      float xx = (p2.x*pv.x + p2.y*pv.y) * idn;
      float xy = (p2.y*pv.x - p2.x*pv.y) * idn;
      Gp[i][ee] = make_float4(-xx, -xx, xy, -xy);
    }
    __syncthreads();
  }
}

// (B,F,C,T) float2 -> masked (B,T,C,F) re/im planes
__global__ __launch_bounds__(256) void k_tout(const float2* __restrict__ enh,
                                              const int* __restrict__ ilens,
                                              float* __restrict__ out_re,
                                              float* __restrict__ out_im) {
  __shared__ float2 tile[32][33];
  int t0 = blockIdx.x * 32, f0 = blockIdx.y * 32;
  int b = blockIdx.z >> 3, c = blockIdx.z & 7;
  int tx = threadIdx.x & 31, ty = threadIdx.x >> 5;
#pragma unroll
  for (int ii = 0; ii < 4; ++ii) {
    int f = f0 + ty + 8 * ii, t = t0 + tx;
    if (f < Ff && t < Tt)
      tile[ty + 8 * ii][tx] = enh[(((size_t)b * Ff + f) * Cc + c) * Tt + t];
  }
  __syncthreads();
  int il = ilens[b];
#pragma unroll
  for (int ii = 0; ii < 4; ++ii) {
    int t = t0 + ty + 8 * ii, f = f0 + tx;
    if (t < Tt && f < Ff) {
      float2 v = tile[tx][ty + 8 * ii];
      if (t >= il) v = make_float2(0.f, 0.f);
      size_t idx = (((size_t)b * Tt + t) * Cc + c) * Ff + f;
      out_re[idx] = v.x;
      out_im[idx] = v.y;
    }
  }
}

extern "C" void kernel_launch(void* const* d_in, const int* in_sizes, int n_in,
                              void* d_out, int out_size, void* d_ws, size_t ws_size,
                              hipStream_t stream) {
  const float* in_re = (const float*)d_in[0];
  const float* in_im = (const float*)d_in[1];
  const int* ilens = (const int*)d_in[2];
  float* out_re = (float*)d_out;
  float* out_im = out_re + NTOT;

  size_t ybytes = (size_t)Bb * Ff * Cc * Tt * sizeof(float2);  // 78,950,400 B
  int have_yt = ws_size >= ybytes;
  // enh ALIASES Yt: k_wpe block bf stages Yt[bf] into LDS before writing enh[bf],
  // and no block touches another block's slice -> race-free, halves ws need.
  float2* Yt  = (float2*)d_ws;
  float2* enh = (float2*)d_ws;

  if (have_yt) {
    dim3 g((Ff + 31) / 32, (Tt + 31) / 32, Bb * Cc);
    k_tin<<<g, dim3(256), 0, stream>>>(in_re, in_im, Yt);
  }
  {
    dim3 g(Bb * Ff);
    k_wpe<<<g, dim3(512), 0, stream>>>(Yt, enh, in_re, in_im, ilens,
                                       out_re, out_im,
                                       have_yt ? 0 : 1, have_yt ? 0 : 1);
  }
  if (have_yt) {
    dim3 g((Tt + 31) / 32, (Ff + 31) / 32, Bb * Cc);
    k_tout<<<g, dim3(256), 0, stream>>>(enh, ilens, out_re, out_im);
  }
}